// Round 5
// baseline (27789.041 us; speedup 1.0000x reference)
//
#include <hip/hip_runtime.h>
#include <hip/hip_bf16.h>

typedef __hip_bfloat16 bf16;
#define DEV __device__ __forceinline__

// ---------------- ws layout (units of f32) ----------------
#define PG_    0L
#define ABUF_  0L
#define DPG0_  8388608L
#define Y0_    16777216L
#define ENCT_  18874368L
#define KB_    20975872L
#define VB_    23073024L
#define ABF_   25170176L
#define TEA_   29364480L
#define P1_    29757696L
#define P2_    30281984L
#define CTXP_  30806272L
#define CTXL_  31080704L
#define QB_    31342848L
#define OB_    33440000L
#define DIN_   35537152L
#define TOP_   35799296L
#define OUTF_  36847872L
#define OUTT_  37503232L
#define PN1_   37902592L
#define PN2_   40032512L
#define WKT_   42162432L
#define WVT_   43342080L
#define WQT_   44521728L
#define W1P_   44734720L
#define PN0T_  44740864L
#define PNMT_  44863744L
#define PN4T_  46829824L
#define HBUF_  46932224L
#define HDEC_  46964992L
#define HFIN_  47030528L
#define CFIN_  47063296L
#define BAR_   47096064L
#define FLAG_  47096320L   // 1 uint
#define CVT_   47096336L
#define WS_NEED_BYTES (52092992L * 4L)

// ---------------- helpers ----------------
DEV float b2f(bf16 x) { return __bfloat162float(x); }
DEV bf16  f2b(float x) { return __float2bfloat16(x); }
DEV float u2f(unsigned u) { union { unsigned i; float f; } c; c.i = u << 16; return c.f; }
DEV unsigned bu(bf16 x) { union { bf16 b; unsigned short u; } c; c.b = x; return (unsigned)c.u; }
DEV unsigned pk2(float a, float b) { return bu(f2b(a)) | (bu(f2b(b)) << 16); }
DEV void unp8(uint4 v, float* o) {
  o[0] = u2f(v.x & 0xffffu); o[1] = u2f(v.x >> 16);
  o[2] = u2f(v.y & 0xffffu); o[3] = u2f(v.y >> 16);
  o[4] = u2f(v.z & 0xffffu); o[5] = u2f(v.z >> 16);
  o[6] = u2f(v.w & 0xffffu); o[7] = u2f(v.w >> 16);
}
DEV float sigm(float x) { return 1.0f / (1.0f + __expf(-x)); }

DEV void gbar(unsigned* cnt, unsigned target) {
  __threadfence();
  __syncthreads();
  if (threadIdx.x == 0) {
    __hip_atomic_fetch_add(cnt, 1u, __ATOMIC_RELEASE, __HIP_MEMORY_SCOPE_AGENT);
    while (__hip_atomic_load(cnt, __ATOMIC_ACQUIRE, __HIP_MEMORY_SCOPE_AGENT) < target) {
      __builtin_amdgcn_s_sleep(2);
    }
  }
  __syncthreads();
  (void)__hip_atomic_load(cnt, __ATOMIC_ACQUIRE, __HIP_MEMORY_SCOPE_AGENT);
}

// ---------------- dtype detect + convert ----------------
__global__ void k_flag(const unsigned short* psw, unsigned* flag) {
  if (threadIdx.x == 0 && blockIdx.x == 0) *flag = (psw[0] != 0) ? 1u : 0u;
}

__global__ void k_cvt(const void* src, bf16* dst, long n, const unsigned* flag) {
  long i = (long)blockIdx.x * 256 + threadIdx.x;
  const long stride = (long)gridDim.x * 256;
  if (*flag) {
    const bf16* s = (const bf16*)src;
    for (; i < n; i += stride) dst[i] = s[i];
  } else {
    const float* s = (const float*)src;
    for (; i < n; i += stride) dst[i] = f2b(s[i]);
  }
}

// ---------------- generic GEMM ----------------
enum { ACT_NONE = 0, ACT_BIAS = 1, ACT_PSINE = 2, ACT_POSTNET = 3, ACT_DECIN = 4, ACT_RESADD = 5 };
enum { SM_F32 = 0, SM_BF16 = 1, SM_PADROW = 2, SM_NCT = 3, SM_TNF32 = 4, SM_RESOUT = 5 };

struct GP {
  const bf16* A; const bf16* B;
  long az, bz, btap;
  int M, N, K, taps;
  int rshift, rpitch;
  float* Cf; bf16* Cb;
  long cz; int cld;
  int p2, pad2, tmax, tp;
  const bf16* bias; long biasz;
  const bf16* s1; const bf16* s2; const bf16* s3;
  const bf16* aux; int auxld;
  const bf16* gamma; const float* res;
};

template<int SM, int ACTM>
__global__ __launch_bounds__(256) void k_gemm(GP p) {
  __shared__ float As[64][36];
  __shared__ float Bs[64][36];
  const int tid = threadIdx.x;
  const int z = blockIdx.z;
  const bf16* Ab = p.A + (long)z * p.az;
  const bf16* Bb = p.B + (long)z * p.bz;
  const int m0 = blockIdx.x * 64, c0 = blockIdx.y * 64;
  const int tx = tid & 15, ty = tid >> 4;
  const int lrow = tid & 63, lk = (tid >> 6) * 8;
  float acc[4][4] = {};
  const int am = m0 + lrow;
  const int grp = am >> p.rshift;
  const long arowbase = (long)grp * p.rpitch + (am - (grp << p.rshift));
  const int brow = c0 + lrow;
  const bool bok = brow < p.N;
  for (int j = 0; j < p.taps; ++j) {
    const bf16* Aj = Ab + (arowbase + j) * (long)p.K + lk;
    const bf16* Bj = Bb + (long)j * p.btap + (long)brow * p.K + lk;
    for (int k0 = 0; k0 < p.K; k0 += 32) {
      __syncthreads();
      {
        uint4 av = *(const uint4*)(Aj + k0);
        float a8[8]; unp8(av, a8);
        #pragma unroll
        for (int q = 0; q < 8; ++q) As[lrow][lk + q] = a8[q];
        uint4 bvv; bvv.x = bvv.y = bvv.z = bvv.w = 0u;
        if (bok) bvv = *(const uint4*)(Bj + k0);
        float b8[8]; unp8(bvv, b8);
        #pragma unroll
        for (int q = 0; q < 8; ++q) Bs[lrow][lk + q] = b8[q];
      }
      __syncthreads();
      #pragma unroll
      for (int kk = 0; kk < 32; kk += 4) {
        float4 a4[4], b4[4];
        #pragma unroll
        for (int i = 0; i < 4; ++i) a4[i] = *(const float4*)&As[ty * 4 + i][kk];
        #pragma unroll
        for (int i = 0; i < 4; ++i) b4[i] = *(const float4*)&Bs[tx * 4 + i][kk];
        #pragma unroll
        for (int i = 0; i < 4; ++i)
          #pragma unroll
          for (int jj = 0; jj < 4; ++jj)
            acc[i][jj] += a4[i].x * b4[jj].x + a4[i].y * b4[jj].y +
                          a4[i].z * b4[jj].z + a4[i].w * b4[jj].w;
      }
    }
  }
  float gf = 0.f;
  if constexpr (ACTM == ACT_DECIN) gf = b2f(p.gamma[0]);
  #pragma unroll
  for (int i = 0; i < 4; ++i) {
    const int m = m0 + ty * 4 + i;
    const int n_ = m >> 8, t_ = m & 255;
    #pragma unroll
    for (int jj = 0; jj < 4; ++jj) {
      const int c = c0 + tx * 4 + jj;
      if (c >= p.N) continue;
      float x = acc[i][jj];
      if constexpr (ACTM == ACT_BIAS) x += b2f(p.bias[(long)z * p.biasz + c]);
      else if constexpr (ACTM == ACT_PSINE) x = sinf(x + b2f(p.bias[c])) * b2f(p.s1[c]);
      else if constexpr (ACTM == ACT_POSTNET) x = sinf((x + b2f(p.bias[c])) * b2f(p.s1[c]) + b2f(p.s2[c])) * b2f(p.s3[c]);
      else if constexpr (ACTM == ACT_DECIN) x = b2f(p.aux[(long)m * p.auxld + c]) + gf * (x + b2f(p.bias[c]));
      else if constexpr (ACTM == ACT_RESADD) x = (x + b2f(p.bias[c])) * b2f(p.s1[c]) + b2f(p.s2[c]);
      if constexpr (SM == SM_F32) p.Cf[(long)z * p.cz + (long)m * p.cld + c] = x;
      else if constexpr (SM == SM_BF16) p.Cb[(long)z * p.cz + (long)m * p.cld + c] = f2b(x);
      else if constexpr (SM == SM_PADROW) p.Cb[((long)n_ * p.p2 + p.pad2 + t_) * (long)p.cld + c] = f2b(x);
      else if constexpr (SM == SM_NCT) { if (t_ < p.tmax) p.Cb[((long)n_ * p.p2 + c) * (long)p.tp + t_] = f2b(x); }
      else if constexpr (SM == SM_TNF32) { const int nn = m & 31, tt = m >> 5; p.Cf[((long)nn * p.p2 + c) * (long)p.tp + tt] = x; }
      else if constexpr (SM == SM_RESOUT) { const long off = ((long)n_ * p.p2 + c) * (long)p.tp + t_; p.Cf[off] = x + p.res[off]; }
    }
  }
}

// ---------------- encoder LSTM scan ----------------
__global__ __launch_bounds__(256) void k_enc_scan(
    const float* __restrict__ pg, const bf16* __restrict__ Whh,
    float* __restrict__ hbuf, bf16* __restrict__ ycat,
    float* __restrict__ hfin, float* __restrict__ cfin,
    int layer, unsigned* __restrict__ bar)
{
  __shared__ bf16  Wl[32][260];
  __shared__ float Hs[32][260];
  __shared__ float Gs[32 * 33];
  const int tid = threadIdx.x;
  const int d = (int)(blockIdx.x >> 5);
  const int u0 = ((int)blockIdx.x & 31) * 8;
  {
    const int r = tid >> 3, seg = tid & 7;
    const int grow = (r >> 3) * 256 + u0 + (r & 7);
    const bf16* wp = Whh + ((long)d * 1024 + grow) * 256 + seg * 32;
    bf16* dst = &Wl[r][seg * 32];
    for (int q = 0; q < 32; q += 8) {
      uint4 v = *(const uint4*)(wp + q);
      *(uint2*)(dst + q)     = make_uint2(v.x, v.y);
      *(uint2*)(dst + q + 4) = make_uint2(v.z, v.w);
    }
  }
  const int pn = tid >> 3, pu = tid & 7;
  float cst = 0.f;
  const int gr0 = u0 + pu, gr1 = 256 + u0 + pu, gr2 = 512 + u0 + pu, gr3 = 768 + u0 + pu;
  const long pgNbase = (long)(d * 32 + pn) * 256 * 1024;
  __syncthreads();
  for (int it = 0; it < 256; ++it) {
    const int s = d ? (255 - it) : it;
    const int par = it & 1;
    {
      const int n = tid >> 3, seg = tid & 7;
      const float* src = hbuf + ((long)(d * 2 + par) * 32 + n) * 256 + seg * 32;
      float* dst = &Hs[n][seg * 32];
      #pragma unroll
      for (int q = 0; q < 32; q += 4) *(float4*)(dst + q) = *(const float4*)(src + q);
    }
    __syncthreads();
    {
      const int r = tid & 31, nq = (tid >> 5) * 4;
      float a0 = 0, a1 = 0, a2 = 0, a3 = 0;
      const bf16* wr = &Wl[r][0];
      const float* x0 = &Hs[nq + 0][0];
      const float* x1 = &Hs[nq + 1][0];
      const float* x2 = &Hs[nq + 2][0];
      const float* x3 = &Hs[nq + 3][0];
      #pragma unroll 4
      for (int k = 0; k < 256; k += 4) {
        uint2 wv = *(const uint2*)(wr + k);
        float w0 = u2f(wv.x & 0xffffu), w1 = u2f(wv.x >> 16);
        float w2 = u2f(wv.y & 0xffffu), w3 = u2f(wv.y >> 16);
        float4 v0 = *(const float4*)(x0 + k);
        float4 v1 = *(const float4*)(x1 + k);
        float4 v2 = *(const float4*)(x2 + k);
        float4 v3 = *(const float4*)(x3 + k);
        a0 += w0 * v0.x + w1 * v0.y + w2 * v0.z + w3 * v0.w;
        a1 += w0 * v1.x + w1 * v1.y + w2 * v1.z + w3 * v1.w;
        a2 += w0 * v2.x + w1 * v2.y + w2 * v2.z + w3 * v2.w;
        a3 += w0 * v3.x + w1 * v3.y + w2 * v3.z + w3 * v3.w;
      }
      Gs[r * 33 + nq + 0] = a0;
      Gs[r * 33 + nq + 1] = a1;
      Gs[r * 33 + nq + 2] = a2;
      Gs[r * 33 + nq + 3] = a3;
    }
    __syncthreads();
    {
      const float* pgs = pg + pgNbase + (long)s * 1024;
      float g0 = Gs[(0 * 8 + pu) * 33 + pn] + pgs[gr0];
      float g1 = Gs[(1 * 8 + pu) * 33 + pn] + pgs[gr1];
      float g2 = Gs[(2 * 8 + pu) * 33 + pn] + pgs[gr2];
      float g3 = Gs[(3 * 8 + pu) * 33 + pn] + pgs[gr3];
      cst = sigm(g1) * cst + sigm(g0) * tanhf(g2);
      float h = sigm(g3) * tanhf(cst);
      hbuf[((long)(d * 2 + (par ^ 1)) * 32 + pn) * 256 + u0 + pu] = h;
      ycat[((long)pn * 256 + s) * 512 + d * 256 + u0 + pu] = f2b(h);
      if (it == 255) {
        hfin[((long)(layer * 2 + d) * 32 + pn) * 256 + u0 + pu] = h;
        cfin[((long)(layer * 2 + d) * 32 + pn) * 256 + u0 + pu] = cst;
      }
    }
    gbar(bar, (unsigned)(it + 1) * (unsigned)gridDim.x);
  }
}

// ---------------- decoder 4-layer LSTM wavefront ----------------
__global__ __launch_bounds__(256) void k_dec_scan(
    const float* __restrict__ dpg0, const bf16* __restrict__ Wih_rest,
    const bf16* __restrict__ Whh, const bf16* __restrict__ dec_b,
    float* __restrict__ hdec, const float* __restrict__ cfin,
    bf16* __restrict__ top, unsigned* __restrict__ bar)
{
  __shared__ bf16 Wl[16][520];
  __shared__ bf16 XH[32][520];
  __shared__ float Gs[16 * 33];
  const int tid = threadIdx.x;
  const int layer = (int)(blockIdx.x >> 6);
  const int u0 = ((int)blockIdx.x & 63) * 4;
  const int kstart = (layer == 0) ? 256 : 0;
  {
    const int r = tid >> 4, seg = tid & 15;
    const int grow = (r >> 2) * 256 + u0 + (r & 3);
    const int kk = seg * 32;
    const bool part0 = kk < 256;
    if (!(part0 && layer == 0)) {
      const bf16* wp = part0
          ? (Wih_rest + ((long)(layer - 1) * 1024 + grow) * 256 + kk)
          : (Whh + ((long)layer * 1024 + grow) * 256 + (kk - 256));
      for (int q = 0; q < 32; q += 8) {
        uint4 v = *(const uint4*)(wp + q);
        *(uint4*)&Wl[r][kk + q] = v;
      }
    }
  }
  const int pn = tid >> 2, pu = tid & 3;
  float cst = 0.f, bi0 = 0.f, bi1 = 0.f, bi2 = 0.f, bi3 = 0.f;
  if (tid < 128) {
    cst = cfin[((long)layer * 32 + pn) * 256 + u0 + pu];
    if (layer > 0) {
      bi0 = b2f(dec_b[layer * 1024 + u0 + pu]);
      bi1 = b2f(dec_b[layer * 1024 + 256 + u0 + pu]);
      bi2 = b2f(dec_b[layer * 1024 + 512 + u0 + pu]);
      bi3 = b2f(dec_b[layer * 1024 + 768 + u0 + pu]);
    }
  }
  __syncthreads();
  for (int dg = 0; dg < 259; ++dg) {
    const int t = dg - layer;
    const bool act = (t >= 0) && (t < 256);
    const int rp = (dg + 1) & 1, wpar = dg & 1;
    if (act) {
      {
        const int n = tid >> 3, seg = tid & 7;
        if (layer > 0 || seg >= 4) {
          const float* src = (seg < 4)
              ? (hdec + ((long)((layer - 1) * 2 + rp) * 32 + n) * 256 + seg * 64)
              : (hdec + ((long)(layer * 2 + rp) * 32 + n) * 256 + (seg - 4) * 64);
          const int base = seg * 64;
          #pragma unroll
          for (int q = 0; q < 64; q += 4) {
            float4 v = *(const float4*)(src + q);
            *(uint2*)&XH[n][base + q] = make_uint2(pk2(v.x, v.y), pk2(v.z, v.w));
          }
        }
      }
      __syncthreads();
      {
        const int r = tid & 15, n0 = (tid >> 4) * 2;
        float a0 = 0, a1 = 0;
        const bf16* wr = &Wl[r][0];
        const bf16* xa = &XH[n0][0];
        const bf16* xb = &XH[n0 + 1][0];
        #pragma unroll 4
        for (int k = kstart; k < 512; k += 4) {
          uint2 wv = *(const uint2*)(wr + k);
          float w0 = u2f(wv.x & 0xffffu), w1 = u2f(wv.x >> 16);
          float w2 = u2f(wv.y & 0xffffu), w3 = u2f(wv.y >> 16);
          uint2 va = *(const uint2*)(xa + k);
          uint2 vb = *(const uint2*)(xb + k);
          a0 += w0 * u2f(va.x & 0xffffu) + w1 * u2f(va.x >> 16) +
                w2 * u2f(va.y & 0xffffu) + w3 * u2f(va.y >> 16);
          a1 += w0 * u2f(vb.x & 0xffffu) + w1 * u2f(vb.x >> 16) +
                w2 * u2f(vb.y & 0xffffu) + w3 * u2f(vb.y >> 16);
        }
        Gs[r * 33 + n0] = a0;
        Gs[r * 33 + n0 + 1] = a1;
      }
      __syncthreads();
      if (tid < 128) {
        float g0 = Gs[(0 * 4 + pu) * 33 + pn] + bi0;
        float g1 = Gs[(1 * 4 + pu) * 33 + pn] + bi1;
        float g2 = Gs[(2 * 4 + pu) * 33 + pn] + bi2;
        float g3 = Gs[(3 * 4 + pu) * 33 + pn] + bi3;
        if (layer == 0) {
          const float* pp = dpg0 + ((long)pn * 256 + t) * 1024;
          g0 += pp[u0 + pu]; g1 += pp[256 + u0 + pu];
          g2 += pp[512 + u0 + pu]; g3 += pp[768 + u0 + pu];
        }
        cst = sigm(g1) * cst + sigm(g0) * tanhf(g2);
        float h = sigm(g3) * tanhf(cst);
        hdec[((long)(layer * 2 + wpar) * 32 + pn) * 256 + u0 + pu] = h;
        if (layer == 3) top[((long)t * 32 + pn) * 256 + u0 + pu] = f2b(h);
      }
    }
    gbar(bar, (unsigned)(dg + 1) * (unsigned)gridDim.x);
  }
}

// ---------------- small kernels ----------------
__global__ void k_wtr(const void* __restrict__ in, bf16* __restrict__ out,
                      int Cout, int Cin, int Cpad, int taps, int tstride, long total,
                      const unsigned* __restrict__ flag) {
  long i = (long)blockIdx.x * 256 + threadIdx.x;
  if (i >= total) return;
  int ci = (int)(i % Cpad); long r = i / Cpad; int co = (int)(r % Cout); int j = (int)(r / Cout);
  float v = 0.f;
  if (ci < Cin) {
    long idx = ((long)co * Cin + ci) * tstride + j;
    v = (*flag) ? b2f(((const bf16*)in)[idx]) : ((const float*)in)[idx];
  }
  out[i] = f2b(v);
}

__global__ void k_softmax(const float* __restrict__ raw, bf16* __restrict__ out) {
  __shared__ float red[256];
  const long row = blockIdx.x;
  const float* r = raw + row * 512;
  const int tid = threadIdx.x;
  float a = r[tid], b = r[tid + 256];
  red[tid] = fmaxf(a, b);
  __syncthreads();
  for (int s = 128; s > 0; s >>= 1) { if (tid < s) red[tid] = fmaxf(red[tid], red[tid + s]); __syncthreads(); }
  const float m = red[0];
  __syncthreads();
  float e0 = __expf(a - m), e1 = __expf(b - m);
  red[tid] = e0 + e1;
  __syncthreads();
  for (int s = 128; s > 0; s >>= 1) { if (tid < s) red[tid] += red[tid + s]; __syncthreads(); }
  const float inv = 1.f / red[0];
  out[row * 512 + tid] = f2b(e0 * inv);
  out[row * 512 + tid + 256] = f2b(e1 * inv);
}

__global__ void k_teacher(const bf16* __restrict__ mels, const bf16* __restrict__ ictx, bf16* __restrict__ out) {
  long i = (long)blockIdx.x * 256 + threadIdx.x;
  if (i >= 8192L * 96) return;
  int c = (int)(i % 96); long m = i / 96; int n = (int)(m >> 8), t = (int)(m & 255);
  float v = 0.f;
  if (c < 80) v = (t == 0) ? b2f(ictx[c]) : b2f(mels[((long)n * 80 + c) * 256 + (t - 1)]);
  out[i] = f2b(v);
}

__global__ void k_ctxcopy(const bf16* __restrict__ ctxp, bf16* __restrict__ ctxl) {
  long i = (long)blockIdx.x * 256 + threadIdx.x;
  if (i >= 8192L * 64) return;
  int c = (int)(i & 63); long m = i >> 6; int n = (int)(m >> 8), t = (int)(m & 255);
  ctxl[i] = ctxp[((long)n * 268 + 12 + t) * 64 + c];
}

__global__ void k_hdec_init(const float* __restrict__ hfin, float* __restrict__ hdec) {
  int i = blockIdx.x * 256 + threadIdx.x;
  if (i >= 32768) return;
  int l = i >> 13, r = i & 8191;
  float v = hfin[i];
  hdec[((long)l * 2 + 0) * 8192 + r] = v;
  hdec[((long)l * 2 + 1) * 8192 + r] = v;
}

__global__ void k_outcopy1(const float* __restrict__ of, float* __restrict__ o) {
  long i = (long)blockIdx.x * 256 + threadIdx.x;
  if (i < 655360L) o[i] = of[i];
}

__global__ void k_outcopy2(const float* __restrict__ of, bf16* __restrict__ ot) {
  long i = (long)blockIdx.x * 256 + threadIdx.x;
  if (i >= 655360L) return;
  int c = (int)(i % 80); long m = i / 80; int n = (int)(m >> 8), t = (int)(m & 255);
  ot[((long)n * 260 + 2 + t) * 96 + c] = f2b(of[((long)n * 80 + c) * 256 + t]);
}

__global__ void k_stop(const bf16* __restrict__ top, const float* __restrict__ hfin,
                       const bf16* __restrict__ sW, const bf16* __restrict__ sb, float* __restrict__ out) {
  int i = blockIdx.x * 256 + threadIdx.x;
  if (i >= 8192) return;
  int n = i >> 8, t = i & 255;
  float acc = b2f(sb[0]);
  const bf16* tr = top + ((long)t * 32 + n) * 256;
  for (int h = 0; h < 256; ++h) acc += b2f(tr[h]) * b2f(sW[h]);
  const float* er = hfin + ((long)2 * 32 + n) * 256;
  for (int h = 0; h < 256; ++h) acc += er[h] * b2f(sW[256 + h]);
  out[(long)n * 256 + t] = acc;
}

// ---------------- host ----------------
extern "C" void kernel_launch(void* const* d_in, const int* in_sizes, int n_in,
                              void* d_out, int out_size, void* d_ws, size_t ws_size,
                              hipStream_t stream) {
  (void)in_sizes; (void)n_in; (void)out_size;
  if (ws_size < (size_t)WS_NEED_BYTES) return;

  float* ws = (float*)d_ws;
  float* out0 = (float*)d_out;            // outputs [32][80][256] f32
  float* out1 = out0 + 655360L;           // post_preds f32
  float* out2 = out0 + 1310720L;          // stop_tokens f32
  #define WF(off) (ws + (off))
  #define WB(off) ((bf16*)(ws + (off)))
  unsigned* bar0 = (unsigned*)WF(BAR_);
  unsigned* bar1 = bar0 + 64;
  unsigned* bar2 = bar0 + 128;
  unsigned* flagp = (unsigned*)WF(FLAG_);

  // zero: barriers, state, padded buffers
  hipMemsetAsync(WF(BAR_), 0, 1024, stream);
  hipMemsetAsync(WF(HBUF_), 0, 32768 * 4, stream);
  hipMemsetAsync(WF(ENCT_), 0, 2101248L * 4, stream);
  hipMemsetAsync(WF(KB_), 0, 2097152L * 4, stream);
  hipMemsetAsync(WF(VB_), 0, 2097152L * 4, stream);
  hipMemsetAsync(WF(CTXP_), 0, 274432L * 4, stream);
  hipMemsetAsync(WF(OUTT_), 0, 399360L * 4, stream);
  hipMemsetAsync(WF(PN1_), 0, 2129920L * 4, stream);
  hipMemsetAsync(WF(PN2_), 0, 2129920L * 4, stream);

  // dtype flag + input conversion
  k_flag<<<dim3(1), dim3(64), 0, stream>>>((const unsigned short*)d_in[44], flagp);
  bf16* cv[48] = {};
  {
    struct CvtEnt { int idx; long n; };
    static const CvtEnt cvts[] = {
      {0, 4194304}, {1, 655360}, {5, 2097152}, {6, 1048576}, {7, 4096},
      {9, 512}, {11, 512}, {13, 512}, {14, 80},
      {16, 128}, {17, 128}, {18, 16384}, {19, 128}, {20, 128}, {21, 8192}, {22, 64},
      {23, 32768}, {24, 64}, {25, 1},
      {26, 65536}, {27, 786432}, {28, 1048576}, {29, 4096},
      {30, 20480}, {31, 80}, {32, 512}, {33, 1},
      {35, 512}, {37, 1536}, {39, 80},
      {40, 2048}, {41, 2048}, {42, 80}, {43, 80}, {44, 2048},
    };
    bf16* arena = WB(CVT_);
    long pos = 0;
    for (const auto& c : cvts) {
      bf16* dst = arena + pos;
      long g = (c.n + 255) / 256; if (g > 2048) g = 2048;
      k_cvt<<<dim3((unsigned)g), dim3(256), 0, stream>>>(d_in[c.idx], dst, c.n, flagp);
      cv[c.idx] = dst;
      pos += (c.n + 15) & ~15L;
    }
  }

  const bf16* enc_out = cv[0];
  const bf16* mels    = cv[1];
  const bf16* eWih    = cv[5];
  const bf16* eWhh    = cv[6];
  const bf16* eb      = cv[7];
  const bf16* bk      = cv[9];
  const bf16* bv      = cv[11];
  const bf16* bq      = cv[13];
  const bf16* ictx    = cv[14];
  const bf16* pb1     = cv[16];
  const bf16* ps1     = cv[17];
  const bf16* pW2     = cv[18];
  const bf16* pb2     = cv[19];
  const bf16* ps2     = cv[20];
  const bf16* pW3     = cv[21];
  const bf16* pb3     = cv[22];
  const bf16* prW     = cv[23];
  const bf16* prb     = cv[24];
  const bf16* gam     = cv[25];
  const bf16* dWih0   = cv[26];
  const bf16* dWihr   = cv[27];
  const bf16* dWhh    = cv[28];
  const bf16* db      = cv[29];
  const bf16* fcW     = cv[30];
  const bf16* fcb     = cv[31];
  const bf16* sW      = cv[32];
  const bf16* sb      = cv[33];
  const bf16* pnb0    = cv[35];
  const bf16* pnbm    = cv[37];
  const bf16* pnb4    = cv[39];
  const bf16* bns     = cv[40];
  const bf16* bnb     = cv[41];
  const bf16* bnso    = cv[42];
  const bf16* bnbo    = cv[43];

  auto tr = [&](const void* in, bf16* o, int Cout, int Cin, int Cpad, int to, int ts) {
    long tot = (long)to * Cout * Cpad;
    k_wtr<<<dim3((unsigned)((tot + 255) / 256)), dim3(256), 0, stream>>>(in, o, Cout, Cin, Cpad, to, ts, tot, flagp);
  };
  tr(d_in[8],  WB(WKT_), 512, 512, 512, 9, 9);
  tr(d_in[10], WB(WVT_), 512, 512, 512, 9, 9);
  tr(d_in[12], WB(WQT_), 512, 64, 64, 13, 24);
  tr(d_in[15], WB(W1P_), 128, 80, 96, 1, 1);
  tr(d_in[34], WB(PN0T_), 512, 80, 96, 5, 5);
  tr(d_in[36], WB(PNMT_), 1536, 512, 512, 5, 5);
  tr(d_in[38], WB(PN4T_), 80, 512, 512, 5, 5);

  // ---- encoder layer 0 ----
  {
    GP p{}; p.A = enc_out; p.az = 0; p.rshift = 8; p.rpitch = 256;
    p.B = eWih; p.bz = 1024L * 512; p.btap = 0;
    p.M = 8192; p.N = 1024; p.K = 512; p.taps = 1;
    p.Cf = WF(PG_); p.cz = 8388608; p.cld = 1024; p.bias = eb; p.biasz = 1024;
    k_gemm<SM_F32, ACT_BIAS><<<dim3(128, 16, 2), dim3(256), 0, stream>>>(p);
  }
  k_enc_scan<<<dim3(64), dim3(256), 0, stream>>>(
      WF(PG_), eWhh, WF(HBUF_), WB(Y0_), WF(HFIN_), WF(CFIN_), 0, bar0);
  hipMemsetAsync(WF(HBUF_), 0, 32768 * 4, stream);
  // ---- encoder layer 1 ----
  {
    GP p{}; p.A = WB(Y0_); p.az = 0; p.rshift = 8; p.rpitch = 256;
    p.B = eWih + 2L * 1024 * 512; p.bz = 1024L * 512; p.btap = 0;
    p.M = 8192; p.N = 1024; p.K = 512; p.taps = 1;
    p.Cf = WF(PG_); p.cz = 8388608; p.cld = 1024; p.bias = eb + 2048; p.biasz = 1024;
    k_gemm<SM_F32, ACT_BIAS><<<dim3(128, 16, 2), dim3(256), 0, stream>>>(p);
  }
  k_enc_scan<<<dim3(64), dim3(256), 0, stream>>>(
      WF(PG_), eWhh + 2L * 1024 * 256, WF(HBUF_), WB(ENCT_), WF(HFIN_), WF(CFIN_), 1, bar1);

  // ---- K/V convs ----
  for (int kv = 0; kv < 2; ++kv) {
    GP p{}; p.A = WB(ENCT_); p.az = 0; p.rshift = 8; p.rpitch = 256;
    p.B = kv ? WB(WVT_) : WB(WKT_); p.bz = 0; p.btap = 512L * 512;
    p.M = 8192; p.N = 512; p.K = 512; p.taps = 9;
    p.Cb = kv ? WB(VB_) : WB(KB_); p.cz = 0; p.cld = 512;
    p.p2 = 512; p.tp = 256; p.tmax = 248; p.bias = kv ? bv : bk; p.biasz = 0;
    k_gemm<SM_NCT, ACT_BIAS><<<dim3(128, 8, 1), dim3(256), 0, stream>>>(p);
  }
  // ---- scores + softmax ----
  {
    GP p{}; p.A = WB(KB_); p.az = 512L * 256; p.rshift = 9; p.rpitch = 512;
    p.B = WB(VB_); p.bz = 512L * 256; p.btap = 0;
    p.M = 512; p.N = 512; p.K = 256; p.taps = 1;
    p.Cf = WF(ABUF_); p.cz = 262144; p.cld = 512;
    k_gemm<SM_F32, ACT_NONE><<<dim3(8, 8, 32), dim3(256), 0, stream>>>(p);
  }
  k_softmax<<<dim3(16384), dim3(256), 0, stream>>>(WF(ABUF_), WB(ABF_));

  // ---- teacher + prenet + context ----
  k_teacher<<<dim3(3072), dim3(256), 0, stream>>>(mels, ictx, WB(TEA_));
  {
    GP p{}; p.A = WB(TEA_); p.az = 0; p.rshift = 8; p.rpitch = 256;
    p.B = WB(W1P_); p.bz = 0; p.btap = 0;
    p.M = 8192; p.N = 128; p.K = 96; p.taps = 1;
    p.Cb = WB(P1_); p.cz = 0; p.cld = 128; p.bias = pb1; p.s1 = ps1;
    k_gemm<SM_BF16, ACT_PSINE><<<dim3(128, 2, 1), dim3(256), 0, stream>>>(p);
  }
  {
    GP p{}; p.A = WB(P1_); p.az = 0; p.rshift = 8; p.rpitch = 256;
    p.B = pW2; p.bz = 0; p.btap = 0;
    p.M = 8192; p.N = 128; p.K = 128; p.taps = 1;
    p.Cb = WB(P2_); p.cz = 0; p.cld = 128; p.bias = pb2; p.s1 = ps2;
    k_gemm<SM_BF16, ACT_PSINE><<<dim3(128, 2, 1), dim3(256), 0, stream>>>(p);
  }
  {
    GP p{}; p.A = WB(P2_); p.az = 0; p.rshift = 8; p.rpitch = 256;
    p.B = pW3; p.bz = 0; p.btap = 0;
    p.M = 8192; p.N = 64; p.K = 128; p.taps = 1;
    p.Cb = WB(CTXP_); p.cz = 0; p.cld = 64; p.p2 = 268; p.pad2 = 12; p.bias = pb3; p.biasz = 0;
    k_gemm<SM_PADROW, ACT_BIAS><<<dim3(128, 1, 1), dim3(256), 0, stream>>>(p);
  }
  k_ctxcopy<<<dim3(2048), dim3(256), 0, stream>>>(WB(CTXP_), WB(CTXL_));

  // ---- causal Q conv ----
  {
    GP p{}; p.A = WB(CTXP_); p.az = 0; p.rshift = 8; p.rpitch = 268;
    p.B = WB(WQT_); p.bz = 0; p.btap = 512L * 64;
    p.M = 8192; p.N = 512; p.K = 64; p.taps = 13;
    p.Cb = WB(QB_); p.cz = 0; p.cld = 512; p.bias = bq; p.biasz = 0;
    k_gemm<SM_BF16, ACT_BIAS><<<dim3(128, 8, 1), dim3(256), 0, stream>>>(p);
  }
  // ---- o = a @ q ----
  {
    GP p{}; p.A = WB(QB_); p.az = 256L * 512; p.rshift = 8; p.rpitch = 256;
    p.B = WB(ABF_); p.bz = 512L * 512; p.btap = 0;
    p.M = 256; p.N = 512; p.K = 512; p.taps = 1;
    p.Cb = WB(OB_); p.cz = 256L * 512; p.cld = 512;
    k_gemm<SM_BF16, ACT_NONE><<<dim3(4, 8, 32), dim3(256), 0, stream>>>(p);
  }
  // ---- dec_in ----
  {
    GP p{}; p.A = WB(OB_); p.az = 0; p.rshift = 8; p.rpitch = 256;
    p.B = prW; p.bz = 0; p.btap = 0;
    p.M = 8192; p.N = 64; p.K = 512; p.taps = 1;
    p.Cb = WB(DIN_); p.cz = 0; p.cld = 64;
    p.bias = prb; p.aux = WB(CTXL_); p.auxld = 64; p.gamma = gam;
    k_gemm<SM_BF16, ACT_DECIN><<<dim3(128, 1, 1), dim3(256), 0, stream>>>(p);
  }
  // ---- decoder layer0 pregates + scan ----
  {
    GP p{}; p.A = WB(DIN_); p.az = 0; p.rshift = 8; p.rpitch = 256;
    p.B = dWih0; p.bz = 0; p.btap = 0;
    p.M = 8192; p.N = 1024; p.K = 64; p.taps = 1;
    p.Cf = WF(DPG0_); p.cz = 0; p.cld = 1024; p.bias = db; p.biasz = 0;
    k_gemm<SM_F32, ACT_BIAS><<<dim3(128, 16, 1), dim3(256), 0, stream>>>(p);
  }
  k_hdec_init<<<dim3(128), dim3(256), 0, stream>>>(WF(HFIN_), WF(HDEC_));
  k_dec_scan<<<dim3(256), dim3(256), 0, stream>>>(
      WF(DPG0_), dWihr, dWhh, db, WF(HDEC_), WF(CFIN_), WB(TOP_), bar2);

  // ---- fc + outputs + stop ----
  {
    GP p{}; p.A = WB(TOP_); p.az = 0; p.rshift = 8; p.rpitch = 256;
    p.B = fcW; p.bz = 0; p.btap = 0;
    p.M = 8192; p.N = 80; p.K = 256; p.taps = 1;
    p.Cf = WF(OUTF_); p.p2 = 80; p.tp = 256; p.bias = fcb; p.biasz = 0;
    k_gemm<SM_TNF32, ACT_BIAS><<<dim3(128, 2, 1), dim3(256), 0, stream>>>(p);
  }
  k_outcopy1<<<dim3(2560), dim3(256), 0, stream>>>(WF(OUTF_), out0);
  k_outcopy2<<<dim3(2560), dim3(256), 0, stream>>>(WF(OUTF_), WB(OUTT_));
  k_stop<<<dim3(32), dim3(256), 0, stream>>>(WB(TOP_), WF(HFIN_), sW, sb, out2);

  // ---- postnet ----
  {
    GP p{}; p.A = WB(OUTT_); p.az = 0; p.rshift = 8; p.rpitch = 260;
    p.B = WB(PN0T_); p.bz = 0; p.btap = 512L * 96;
    p.M = 8192; p.N = 512; p.K = 96; p.taps = 5;
    p.Cb = WB(PN1_); p.cz = 0; p.cld = 512; p.p2 = 260; p.pad2 = 2;
    p.bias = pnb0; p.s1 = bns; p.s2 = bnb; p.s3 = cv[44];
    k_gemm<SM_PADROW, ACT_POSTNET><<<dim3(128, 8, 1), dim3(256), 0, stream>>>(p);
  }
  for (int s3 = 0; s3 < 3; ++s3) {
    GP p{}; p.A = (s3 & 1) ? WB(PN2_) : WB(PN1_); p.az = 0; p.rshift = 8; p.rpitch = 260;
    p.B = WB(PNMT_) + (long)s3 * 512 * 512; p.bz = 0; p.btap = 1536L * 512;
    p.M = 8192; p.N = 512; p.K = 512; p.taps = 5;
    p.Cb = (s3 & 1) ? WB(PN1_) : WB(PN2_); p.cz = 0; p.cld = 512; p.p2 = 260; p.pad2 = 2;
    p.bias = pnbm + s3 * 512; p.s1 = bns + (s3 + 1) * 512; p.s2 = bnb + (s3 + 1) * 512; p.s3 = cv[44] + (s3 + 1) * 512;
    k_gemm<SM_PADROW, ACT_POSTNET><<<dim3(128, 8, 1), dim3(256), 0, stream>>>(p);
  }
  {
    GP p{}; p.A = WB(PN2_); p.az = 0; p.rshift = 8; p.rpitch = 260;
    p.B = WB(PN4T_); p.bz = 0; p.btap = 80L * 512;
    p.M = 8192; p.N = 80; p.K = 512; p.taps = 5;
    p.Cf = out1; p.p2 = 80; p.tp = 256;
    p.bias = pnb4; p.s1 = bnso; p.s2 = bnbo; p.res = WF(OUTF_);
    k_gemm<SM_RESOUT, ACT_RESADD><<<dim3(128, 2, 1), dim3(256), 0, stream>>>(p);
  }
}

// Round 6
// 23492.334 us; speedup vs baseline: 1.1829x; 1.1829x over previous
//
#include <hip/hip_runtime.h>
#include <hip/hip_bf16.h>

typedef __hip_bfloat16 bf16;
#define DEV __device__ __forceinline__

// ---------------- ws layout (units of f32) ----------------
#define PG_    0L
#define ABUF_  0L          // also decoder flag region (16KB) after softmax consumed it
#define DPG0_  8388608L
#define Y0_    16777216L
#define ENCT_  18874368L
#define KB_    20975872L
#define VB_    23073024L
#define ABF_   25170176L
#define TEA_   29364480L
#define P1_    29757696L
#define P2_    30281984L
#define CTXP_  30806272L
#define CTXL_  31080704L
#define QB_    31342848L
#define OB_    33440000L
#define DIN_   35537152L
#define TOP_   35799296L
#define OUTF_  36847872L
#define OUTT_  37503232L
#define PN1_   37902592L
#define PN2_   40032512L
#define WKT_   42162432L
#define WVT_   43342080L
#define WQT_   44521728L
#define W1P_   44734720L
#define PN0T_  44740864L
#define PNMT_  44863744L
#define PN4T_  46829824L
#define HDEC_  46964992L
#define HFIN_  47030528L
#define CFIN_  47063296L
#define FLAG_  47096320L   // 1 uint
#define CVT_   47096336L
#define WS_NEED_BYTES (52092992L * 4L)

// ---------------- helpers ----------------
DEV float b2f(bf16 x) { return __bfloat162float(x); }
DEV bf16  f2b(float x) { return __float2bfloat16(x); }
DEV float u2f(unsigned u) { union { unsigned i; float f; } c; c.i = u << 16; return c.f; }
DEV unsigned bu(bf16 x) { union { bf16 b; unsigned short u; } c; c.b = x; return (unsigned)c.u; }
DEV unsigned pk2(float a, float b) { return bu(f2b(a)) | (bu(f2b(b)) << 16); }
DEV void unp8(uint4 v, float* o) {
  o[0] = u2f(v.x & 0xffffu); o[1] = u2f(v.x >> 16);
  o[2] = u2f(v.y & 0xffffu); o[3] = u2f(v.y >> 16);
  o[4] = u2f(v.z & 0xffffu); o[5] = u2f(v.z >> 16);
  o[6] = u2f(v.w & 0xffffu); o[7] = u2f(v.w >> 16);
}
DEV float sigm(float x) { return 1.0f / (1.0f + __expf(-x)); }

// single-writer monotonic flag spin (no RMW contention)
DEV void spin_ge(unsigned* f, unsigned tgt) {
  while (__hip_atomic_load(f, __ATOMIC_ACQUIRE, __HIP_MEMORY_SCOPE_AGENT) < tgt)
    __builtin_amdgcn_s_sleep(2);
}

// ---------------- dtype detect + convert ----------------
__global__ void k_flag(const unsigned short* psw, unsigned* flag) {
  if (threadIdx.x == 0 && blockIdx.x == 0) *flag = (psw[0] != 0) ? 1u : 0u;
}

__global__ void k_cvt(const void* src, bf16* dst, long n, const unsigned* flag) {
  long i = (long)blockIdx.x * 256 + threadIdx.x;
  const long stride = (long)gridDim.x * 256;
  if (*flag) {
    const bf16* s = (const bf16*)src;
    for (; i < n; i += stride) dst[i] = s[i];
  } else {
    const float* s = (const float*)src;
    for (; i < n; i += stride) dst[i] = f2b(s[i]);
  }
}

// ---------------- generic GEMM ----------------
enum { ACT_NONE = 0, ACT_BIAS = 1, ACT_PSINE = 2, ACT_POSTNET = 3, ACT_DECIN = 4, ACT_RESADD = 5 };
enum { SM_F32 = 0, SM_BF16 = 1, SM_PADROW = 2, SM_NCT = 3, SM_TNF32 = 4, SM_RESOUT = 5 };

struct GP {
  const bf16* A; const bf16* B;
  long az, bz, btap;
  int M, N, K, taps;
  int rshift, rpitch;
  float* Cf; bf16* Cb;
  long cz; int cld;
  int p2, pad2, tmax, tp;
  const bf16* bias; long biasz;
  const bf16* s1; const bf16* s2; const bf16* s3;
  const bf16* aux; int auxld;
  const bf16* gamma; const float* res;
};

template<int SM, int ACTM>
__global__ __launch_bounds__(256) void k_gemm(GP p) {
  __shared__ float As[64][36];
  __shared__ float Bs[64][36];
  const int tid = threadIdx.x;
  const int z = blockIdx.z;
  const bf16* Ab = p.A + (long)z * p.az;
  const bf16* Bb = p.B + (long)z * p.bz;
  const int m0 = blockIdx.x * 64, c0 = blockIdx.y * 64;
  const int tx = tid & 15, ty = tid >> 4;
  const int lrow = tid & 63, lk = (tid >> 6) * 8;
  float acc[4][4] = {};
  const int am = m0 + lrow;
  const int grp = am >> p.rshift;
  const long arowbase = (long)grp * p.rpitch + (am - (grp << p.rshift));
  const int brow = c0 + lrow;
  const bool bok = brow < p.N;
  for (int j = 0; j < p.taps; ++j) {
    const bf16* Aj = Ab + (arowbase + j) * (long)p.K + lk;
    const bf16* Bj = Bb + (long)j * p.btap + (long)brow * p.K + lk;
    for (int k0 = 0; k0 < p.K; k0 += 32) {
      __syncthreads();
      {
        uint4 av = *(const uint4*)(Aj + k0);
        float a8[8]; unp8(av, a8);
        #pragma unroll
        for (int q = 0; q < 8; ++q) As[lrow][lk + q] = a8[q];
        uint4 bvv; bvv.x = bvv.y = bvv.z = bvv.w = 0u;
        if (bok) bvv = *(const uint4*)(Bj + k0);
        float b8[8]; unp8(bvv, b8);
        #pragma unroll
        for (int q = 0; q < 8; ++q) Bs[lrow][lk + q] = b8[q];
      }
      __syncthreads();
      #pragma unroll
      for (int kk = 0; kk < 32; kk += 4) {
        float4 a4[4], b4[4];
        #pragma unroll
        for (int i = 0; i < 4; ++i) a4[i] = *(const float4*)&As[ty * 4 + i][kk];
        #pragma unroll
        for (int i = 0; i < 4; ++i) b4[i] = *(const float4*)&Bs[tx * 4 + i][kk];
        #pragma unroll
        for (int i = 0; i < 4; ++i)
          #pragma unroll
          for (int jj = 0; jj < 4; ++jj)
            acc[i][jj] += a4[i].x * b4[jj].x + a4[i].y * b4[jj].y +
                          a4[i].z * b4[jj].z + a4[i].w * b4[jj].w;
      }
    }
  }
  float gf = 0.f;
  if constexpr (ACTM == ACT_DECIN) gf = b2f(p.gamma[0]);
  #pragma unroll
  for (int i = 0; i < 4; ++i) {
    const int m = m0 + ty * 4 + i;
    const int n_ = m >> 8, t_ = m & 255;
    #pragma unroll
    for (int jj = 0; jj < 4; ++jj) {
      const int c = c0 + tx * 4 + jj;
      if (c >= p.N) continue;
      float x = acc[i][jj];
      if constexpr (ACTM == ACT_BIAS) x += b2f(p.bias[(long)z * p.biasz + c]);
      else if constexpr (ACTM == ACT_PSINE) x = sinf(x + b2f(p.bias[c])) * b2f(p.s1[c]);
      else if constexpr (ACTM == ACT_POSTNET) x = sinf((x + b2f(p.bias[c])) * b2f(p.s1[c]) + b2f(p.s2[c])) * b2f(p.s3[c]);
      else if constexpr (ACTM == ACT_DECIN) x = b2f(p.aux[(long)m * p.auxld + c]) + gf * (x + b2f(p.bias[c]));
      else if constexpr (ACTM == ACT_RESADD) x = (x + b2f(p.bias[c])) * b2f(p.s1[c]) + b2f(p.s2[c]);
      if constexpr (SM == SM_F32) p.Cf[(long)z * p.cz + (long)m * p.cld + c] = x;
      else if constexpr (SM == SM_BF16) p.Cb[(long)z * p.cz + (long)m * p.cld + c] = f2b(x);
      else if constexpr (SM == SM_PADROW) p.Cb[((long)n_ * p.p2 + p.pad2 + t_) * (long)p.cld + c] = f2b(x);
      else if constexpr (SM == SM_NCT) { if (t_ < p.tmax) p.Cb[((long)n_ * p.p2 + c) * (long)p.tp + t_] = f2b(x); }
      else if constexpr (SM == SM_TNF32) { const int nn = m & 31, tt = m >> 5; p.Cf[((long)nn * p.p2 + c) * (long)p.tp + tt] = x; }
      else if constexpr (SM == SM_RESOUT) { const long off = ((long)n_ * p.p2 + c) * (long)p.tp + t_; p.Cf[off] = x + p.res[off]; }
    }
  }
}

// ---------------- encoder LSTM scan: one block per (dir, batch), zero cross-block sync ----
__global__ __launch_bounds__(256) void k_enc_scan(
    const float* __restrict__ pg,      // [2][32][256][1024]
    const bf16* __restrict__ Whh,      // [2][1024][256] for this layer
    bf16* __restrict__ ycat,           // [32][256][512]
    float* __restrict__ hfin, float* __restrict__ cfin,
    int layer)
{
  __shared__ float Hs[2][256];
  const int u = threadIdx.x;
  const int d = (int)(blockIdx.x >> 5);
  const int n = (int)(blockIdx.x & 31);
  const bf16* wr0 = Whh + ((long)d * 1024 +       u) * 256;
  const bf16* wr1 = Whh + ((long)d * 1024 + 256 + u) * 256;
  const bf16* wr2 = Whh + ((long)d * 1024 + 512 + u) * 256;
  const bf16* wr3 = Whh + ((long)d * 1024 + 768 + u) * 256;
  const float* pgn = pg + (long)(d * 32 + n) * 256 * 1024;
  float cst = 0.f;
  Hs[0][u] = 0.f;
  __syncthreads();
  for (int it = 0; it < 256; ++it) {
    const int s = d ? (255 - it) : it;
    const int par = it & 1;
    const float* pgs = pgn + (long)s * 1024;
    float a0 = pgs[u], a1 = pgs[256 + u], a2 = pgs[512 + u], a3 = pgs[768 + u];
    const float* hp = &Hs[par][0];
    #pragma unroll 2
    for (int k = 0; k < 256; k += 8) {
      float x0[4], x1[4], w[8];
      *(float4*)&x0[0] = *(const float4*)(hp + k);
      *(float4*)&x1[0] = *(const float4*)(hp + k + 4);
      unp8(*(const uint4*)(wr0 + k), w);
      a0 += w[0]*x0[0] + w[1]*x0[1] + w[2]*x0[2] + w[3]*x0[3]
          + w[4]*x1[0] + w[5]*x1[1] + w[6]*x1[2] + w[7]*x1[3];
      unp8(*(const uint4*)(wr1 + k), w);
      a1 += w[0]*x0[0] + w[1]*x0[1] + w[2]*x0[2] + w[3]*x0[3]
          + w[4]*x1[0] + w[5]*x1[1] + w[6]*x1[2] + w[7]*x1[3];
      unp8(*(const uint4*)(wr2 + k), w);
      a2 += w[0]*x0[0] + w[1]*x0[1] + w[2]*x0[2] + w[3]*x0[3]
          + w[4]*x1[0] + w[5]*x1[1] + w[6]*x1[2] + w[7]*x1[3];
      unp8(*(const uint4*)(wr3 + k), w);
      a3 += w[0]*x0[0] + w[1]*x0[1] + w[2]*x0[2] + w[3]*x0[3]
          + w[4]*x1[0] + w[5]*x1[1] + w[6]*x1[2] + w[7]*x1[3];
    }
    cst = sigm(a1) * cst + sigm(a0) * tanhf(a2);
    float h = sigm(a3) * tanhf(cst);
    __syncthreads();
    Hs[par ^ 1][u] = h;
    ycat[((long)n * 256 + s) * 512 + d * 256 + u] = f2b(h);
    if (it == 255) {
      hfin[((long)(layer * 2 + d) * 32 + n) * 256 + u] = h;
      cfin[((long)(layer * 2 + d) * 32 + n) * 256 + u] = cst;
    }
    __syncthreads();
  }
}

// ---------------- decoder 4-layer LSTM: flag-based dataflow pipeline ----------------
// 256 blocks = 4 layers x 64 unit-groups. Per-block single-writer step flags; no global barrier.
__global__ __launch_bounds__(256) void k_dec_scan(
    const float* __restrict__ dpg0,     // [32][256][1024]
    const bf16* __restrict__ Wih_rest,  // [3][1024][256]
    const bf16* __restrict__ Whh,       // [4][1024][256]
    const bf16* __restrict__ dec_b,     // [4][1024]
    float* __restrict__ hdec,           // [4][2][32][256]
    const float* __restrict__ cfin,     // [4][32][256]
    bf16* __restrict__ top,             // [256][32][256]
    unsigned* __restrict__ flags)       // [256] x stride 16 u32 (64B)
{
  __shared__ bf16 Wl[16][520];
  __shared__ bf16 XH[32][524];
  __shared__ float Gs[16 * 33];
  const int tid = threadIdx.x;
  const int layer = (int)(blockIdx.x >> 6);
  const int g = (int)(blockIdx.x & 63);
  const int u0 = g * 4;
  const int kstart = (layer == 0) ? 256 : 0;
  {
    const int r = tid >> 4, seg = tid & 15;
    const int grow = (r >> 2) * 256 + u0 + (r & 3);
    const int kk = seg * 32;
    const bool part0 = kk < 256;
    if (!(part0 && layer == 0)) {
      const bf16* wp = part0
          ? (Wih_rest + ((long)(layer - 1) * 1024 + grow) * 256 + kk)
          : (Whh + ((long)layer * 1024 + grow) * 256 + (kk - 256));
      for (int q = 0; q < 32; q += 8) {
        uint4 v = *(const uint4*)(wp + q);
        *(uint4*)&Wl[r][kk + q] = v;
      }
    }
  }
  const int pn = tid >> 2, pu = tid & 3;
  float cst = 0.f, bi0 = 0.f, bi1 = 0.f, bi2 = 0.f, bi3 = 0.f;
  if (tid < 128) {
    cst = cfin[((long)layer * 32 + pn) * 256 + u0 + pu];
    if (layer > 0) {
      bi0 = b2f(dec_b[layer * 1024 + u0 + pu]);
      bi1 = b2f(dec_b[layer * 1024 + 256 + u0 + pu]);
      bi2 = b2f(dec_b[layer * 1024 + 512 + u0 + pu]);
      bi3 = b2f(dec_b[layer * 1024 + 768 + u0 + pu]);
    }
  }
  __syncthreads();
  for (int t = 0; t < 256; ++t) {
    // dependency wait: parallel pollers, one flag each
    if (tid < 64) {
      if (layer > 0) spin_ge(&flags[((layer - 1) * 64 + tid) * 16], (unsigned)(t + 1));
    } else if (tid < 128) {
      if (t >= 1) spin_ge(&flags[(layer * 64 + (tid - 64)) * 16], (unsigned)t);
    } else if (tid < 192) {
      if (layer < 3 && t >= 2) spin_ge(&flags[((layer + 1) * 64 + (tid - 128)) * 16], (unsigned)(t - 1));
    }
    __syncthreads();
    const int rp = (t + layer + 1) & 1, wpar = (t + layer) & 1;
    {
      const int n = tid >> 3, seg = tid & 7;
      if (layer > 0 || seg >= 4) {
        const float* src = (seg < 4)
            ? (hdec + ((long)((layer - 1) * 2 + rp) * 32 + n) * 256 + seg * 64)
            : (hdec + ((long)(layer * 2 + rp) * 32 + n) * 256 + (seg - 4) * 64);
        const int base = seg * 64;
        #pragma unroll
        for (int q = 0; q < 64; q += 4) {
          float4 v = *(const float4*)(src + q);
          *(uint2*)&XH[n][base + q] = make_uint2(pk2(v.x, v.y), pk2(v.z, v.w));
        }
      }
    }
    __syncthreads();
    {
      const int r = tid & 15, n0 = (tid >> 4) * 2;
      float a0 = 0, a1 = 0;
      const bf16* wr = &Wl[r][0];
      const bf16* xa = &XH[n0][0];
      const bf16* xb = &XH[n0 + 1][0];
      #pragma unroll 4
      for (int k = kstart; k < 512; k += 4) {
        uint2 wv = *(const uint2*)(wr + k);
        float w0 = u2f(wv.x & 0xffffu), w1 = u2f(wv.x >> 16);
        float w2 = u2f(wv.y & 0xffffu), w3 = u2f(wv.y >> 16);
        uint2 va = *(const uint2*)(xa + k);
        uint2 vb = *(const uint2*)(xb + k);
        a0 += w0 * u2f(va.x & 0xffffu) + w1 * u2f(va.x >> 16) +
              w2 * u2f(va.y & 0xffffu) + w3 * u2f(va.y >> 16);
        a1 += w0 * u2f(vb.x & 0xffffu) + w1 * u2f(vb.x >> 16) +
              w2 * u2f(vb.y & 0xffffu) + w3 * u2f(vb.y >> 16);
      }
      Gs[r * 33 + n0] = a0;
      Gs[r * 33 + n0 + 1] = a1;
    }
    __syncthreads();
    if (tid < 128) {
      float g0 = Gs[(0 * 4 + pu) * 33 + pn] + bi0;
      float g1 = Gs[(1 * 4 + pu) * 33 + pn] + bi1;
      float g2 = Gs[(2 * 4 + pu) * 33 + pn] + bi2;
      float g3 = Gs[(3 * 4 + pu) * 33 + pn] + bi3;
      if (layer == 0) {
        const float* pp = dpg0 + ((long)pn * 256 + t) * 1024;
        g0 += pp[u0 + pu]; g1 += pp[256 + u0 + pu];
        g2 += pp[512 + u0 + pu]; g3 += pp[768 + u0 + pu];
      }
      cst = sigm(g1) * cst + sigm(g0) * tanhf(g2);
      float h = sigm(g3) * tanhf(cst);
      hdec[((long)(layer * 2 + wpar) * 32 + pn) * 256 + u0 + pu] = h;
      if (layer == 3) top[((long)t * 32 + pn) * 256 + u0 + pu] = f2b(h);
    }
    __threadfence();
    __syncthreads();
    if (tid == 0)
      __hip_atomic_store(&flags[(layer * 64 + g) * 16], (unsigned)(t + 1),
                         __ATOMIC_RELEASE, __HIP_MEMORY_SCOPE_AGENT);
  }
}

// ---------------- small kernels ----------------
__global__ void k_wtr(const void* __restrict__ in, bf16* __restrict__ out,
                      int Cout, int Cin, int Cpad, int taps, int tstride, long total,
                      const unsigned* __restrict__ flag) {
  long i = (long)blockIdx.x * 256 + threadIdx.x;
  if (i >= total) return;
  int ci = (int)(i % Cpad); long r = i / Cpad; int co = (int)(r % Cout); int j = (int)(r / Cout);
  float v = 0.f;
  if (ci < Cin) {
    long idx = ((long)co * Cin + ci) * tstride + j;
    v = (*flag) ? b2f(((const bf16*)in)[idx]) : ((const float*)in)[idx];
  }
  out[i] = f2b(v);
}

__global__ void k_softmax(const float* __restrict__ raw, bf16* __restrict__ out) {
  __shared__ float red[256];
  const long row = blockIdx.x;
  const float* r = raw + row * 512;
  const int tid = threadIdx.x;
  float a = r[tid], b = r[tid + 256];
  red[tid] = fmaxf(a, b);
  __syncthreads();
  for (int s = 128; s > 0; s >>= 1) { if (tid < s) red[tid] = fmaxf(red[tid], red[tid + s]); __syncthreads(); }
  const float m = red[0];
  __syncthreads();
  float e0 = __expf(a - m), e1 = __expf(b - m);
  red[tid] = e0 + e1;
  __syncthreads();
  for (int s = 128; s > 0; s >>= 1) { if (tid < s) red[tid] += red[tid + s]; __syncthreads(); }
  const float inv = 1.f / red[0];
  out[row * 512 + tid] = f2b(e0 * inv);
  out[row * 512 + tid + 256] = f2b(e1 * inv);
}

__global__ void k_teacher(const bf16* __restrict__ mels, const bf16* __restrict__ ictx, bf16* __restrict__ out) {
  long i = (long)blockIdx.x * 256 + threadIdx.x;
  if (i >= 8192L * 96) return;
  int c = (int)(i % 96); long m = i / 96; int n = (int)(m >> 8), t = (int)(m & 255);
  float v = 0.f;
  if (c < 80) v = (t == 0) ? b2f(ictx[c]) : b2f(mels[((long)n * 80 + c) * 256 + (t - 1)]);
  out[i] = f2b(v);
}

__global__ void k_ctxcopy(const bf16* __restrict__ ctxp, bf16* __restrict__ ctxl) {
  long i = (long)blockIdx.x * 256 + threadIdx.x;
  if (i >= 8192L * 64) return;
  int c = (int)(i & 63); long m = i >> 6; int n = (int)(m >> 8), t = (int)(m & 255);
  ctxl[i] = ctxp[((long)n * 268 + 12 + t) * 64 + c];
}

__global__ void k_hdec_init(const float* __restrict__ hfin, float* __restrict__ hdec) {
  int i = blockIdx.x * 256 + threadIdx.x;
  if (i >= 32768) return;
  int l = i >> 13, r = i & 8191;
  float v = hfin[i];
  hdec[((long)l * 2 + 0) * 8192 + r] = v;
  hdec[((long)l * 2 + 1) * 8192 + r] = v;
}

__global__ void k_outcopy1(const float* __restrict__ of, float* __restrict__ o) {
  long i = (long)blockIdx.x * 256 + threadIdx.x;
  if (i < 655360L) o[i] = of[i];
}

__global__ void k_outcopy2(const float* __restrict__ of, bf16* __restrict__ ot) {
  long i = (long)blockIdx.x * 256 + threadIdx.x;
  if (i >= 655360L) return;
  int c = (int)(i % 80); long m = i / 80; int n = (int)(m >> 8), t = (int)(m & 255);
  ot[((long)n * 260 + 2 + t) * 96 + c] = f2b(of[((long)n * 80 + c) * 256 + t]);
}

__global__ void k_stop(const bf16* __restrict__ top, const float* __restrict__ hfin,
                       const bf16* __restrict__ sW, const bf16* __restrict__ sb, float* __restrict__ out) {
  int i = blockIdx.x * 256 + threadIdx.x;
  if (i >= 8192) return;
  int n = i >> 8, t = i & 255;
  float acc = b2f(sb[0]);
  const bf16* tr = top + ((long)t * 32 + n) * 256;
  for (int h = 0; h < 256; ++h) acc += b2f(tr[h]) * b2f(sW[h]);
  const float* er = hfin + ((long)2 * 32 + n) * 256;
  for (int h = 0; h < 256; ++h) acc += er[h] * b2f(sW[256 + h]);
  out[(long)n * 256 + t] = acc;
}

// ---------------- host ----------------
extern "C" void kernel_launch(void* const* d_in, const int* in_sizes, int n_in,
                              void* d_out, int out_size, void* d_ws, size_t ws_size,
                              hipStream_t stream) {
  (void)in_sizes; (void)n_in; (void)out_size;
  if (ws_size < (size_t)WS_NEED_BYTES) return;

  float* ws = (float*)d_ws;
  float* out0 = (float*)d_out;
  float* out1 = out0 + 655360L;
  float* out2 = out0 + 1310720L;
  #define WF(off) (ws + (off))
  #define WB(off) ((bf16*)(ws + (off)))
  unsigned* flagp = (unsigned*)WF(FLAG_);

  // zero padded buffers
  hipMemsetAsync(WF(ENCT_), 0, 2101248L * 4, stream);
  hipMemsetAsync(WF(KB_), 0, 2097152L * 4, stream);
  hipMemsetAsync(WF(VB_), 0, 2097152L * 4, stream);
  hipMemsetAsync(WF(CTXP_), 0, 274432L * 4, stream);
  hipMemsetAsync(WF(OUTT_), 0, 399360L * 4, stream);
  hipMemsetAsync(WF(PN1_), 0, 2129920L * 4, stream);
  hipMemsetAsync(WF(PN2_), 0, 2129920L * 4, stream);

  // dtype flag + input conversion
  k_flag<<<dim3(1), dim3(64), 0, stream>>>((const unsigned short*)d_in[44], flagp);
  bf16* cv[48] = {};
  {
    struct CvtEnt { int idx; long n; };
    static const CvtEnt cvts[] = {
      {0, 4194304}, {1, 655360}, {5, 2097152}, {6, 1048576}, {7, 4096},
      {9, 512}, {11, 512}, {13, 512}, {14, 80},
      {16, 128}, {17, 128}, {18, 16384}, {19, 128}, {20, 128}, {21, 8192}, {22, 64},
      {23, 32768}, {24, 64}, {25, 1},
      {26, 65536}, {27, 786432}, {28, 1048576}, {29, 4096},
      {30, 20480}, {31, 80}, {32, 512}, {33, 1},
      {35, 512}, {37, 1536}, {39, 80},
      {40, 2048}, {41, 2048}, {42, 80}, {43, 80}, {44, 2048},
    };
    bf16* arena = WB(CVT_);
    long pos = 0;
    for (const auto& c : cvts) {
      bf16* dst = arena + pos;
      long g = (c.n + 255) / 256; if (g > 2048) g = 2048;
      k_cvt<<<dim3((unsigned)g), dim3(256), 0, stream>>>(d_in[c.idx], dst, c.n, flagp);
      cv[c.idx] = dst;
      pos += (c.n + 15) & ~15L;
    }
  }

  const bf16* enc_out = cv[0];
  const bf16* mels    = cv[1];
  const bf16* eWih    = cv[5];
  const bf16* eWhh    = cv[6];
  const bf16* eb      = cv[7];
  const bf16* bk      = cv[9];
  const bf16* bv      = cv[11];
  const bf16* bq      = cv[13];
  const bf16* ictx    = cv[14];
  const bf16* pb1     = cv[16];
  const bf16* ps1     = cv[17];
  const bf16* pW2     = cv[18];
  const bf16* pb2     = cv[19];
  const bf16* ps2     = cv[20];
  const bf16* pW3     = cv[21];
  const bf16* pb3     = cv[22];
  const bf16* prW     = cv[23];
  const bf16* prb     = cv[24];
  const bf16* gam     = cv[25];
  const bf16* dWih0   = cv[26];
  const bf16* dWihr   = cv[27];
  const bf16* dWhh    = cv[28];
  const bf16* db      = cv[29];
  const bf16* fcW     = cv[30];
  const bf16* fcb     = cv[31];
  const bf16* sW      = cv[32];
  const bf16* sb      = cv[33];
  const bf16* pnb0    = cv[35];
  const bf16* pnbm    = cv[37];
  const bf16* pnb4    = cv[39];
  const bf16* bns     = cv[40];
  const bf16* bnb     = cv[41];
  const bf16* bnso    = cv[42];
  const bf16* bnbo    = cv[43];

  auto tr = [&](const void* in, bf16* o, int Cout, int Cin, int Cpad, int to, int ts) {
    long tot = (long)to * Cout * Cpad;
    k_wtr<<<dim3((unsigned)((tot + 255) / 256)), dim3(256), 0, stream>>>(in, o, Cout, Cin, Cpad, to, ts, tot, flagp);
  };
  tr(d_in[8],  WB(WKT_), 512, 512, 512, 9, 9);
  tr(d_in[10], WB(WVT_), 512, 512, 512, 9, 9);
  tr(d_in[12], WB(WQT_), 512, 64, 64, 13, 24);
  tr(d_in[15], WB(W1P_), 128, 80, 96, 1, 1);
  tr(d_in[34], WB(PN0T_), 512, 80, 96, 5, 5);
  tr(d_in[36], WB(PNMT_), 1536, 512, 512, 5, 5);
  tr(d_in[38], WB(PN4T_), 80, 512, 512, 5, 5);

  // ---- encoder layer 0 ----
  {
    GP p{}; p.A = enc_out; p.az = 0; p.rshift = 8; p.rpitch = 256;
    p.B = eWih; p.bz = 1024L * 512; p.btap = 0;
    p.M = 8192; p.N = 1024; p.K = 512; p.taps = 1;
    p.Cf = WF(PG_); p.cz = 8388608; p.cld = 1024; p.bias = eb; p.biasz = 1024;
    k_gemm<SM_F32, ACT_BIAS><<<dim3(128, 16, 2), dim3(256), 0, stream>>>(p);
  }
  k_enc_scan<<<dim3(64), dim3(256), 0, stream>>>(
      WF(PG_), eWhh, WB(Y0_), WF(HFIN_), WF(CFIN_), 0);
  // ---- encoder layer 1 ----
  {
    GP p{}; p.A = WB(Y0_); p.az = 0; p.rshift = 8; p.rpitch = 256;
    p.B = eWih + 2L * 1024 * 512; p.bz = 1024L * 512; p.btap = 0;
    p.M = 8192; p.N = 1024; p.K = 512; p.taps = 1;
    p.Cf = WF(PG_); p.cz = 8388608; p.cld = 1024; p.bias = eb + 2048; p.biasz = 1024;
    k_gemm<SM_F32, ACT_BIAS><<<dim3(128, 16, 2), dim3(256), 0, stream>>>(p);
  }
  k_enc_scan<<<dim3(64), dim3(256), 0, stream>>>(
      WF(PG_), eWhh + 2L * 1024 * 256, WB(ENCT_), WF(HFIN_), WF(CFIN_), 1);

  // ---- K/V convs ----
  for (int kv = 0; kv < 2; ++kv) {
    GP p{}; p.A = WB(ENCT_); p.az = 0; p.rshift = 8; p.rpitch = 256;
    p.B = kv ? WB(WVT_) : WB(WKT_); p.bz = 0; p.btap = 512L * 512;
    p.M = 8192; p.N = 512; p.K = 512; p.taps = 9;
    p.Cb = kv ? WB(VB_) : WB(KB_); p.cz = 0; p.cld = 512;
    p.p2 = 512; p.tp = 256; p.tmax = 248; p.bias = kv ? bv : bk; p.biasz = 0;
    k_gemm<SM_NCT, ACT_BIAS><<<dim3(128, 8, 1), dim3(256), 0, stream>>>(p);
  }
  // ---- scores + softmax ----
  {
    GP p{}; p.A = WB(KB_); p.az = 512L * 256; p.rshift = 9; p.rpitch = 512;
    p.B = WB(VB_); p.bz = 512L * 256; p.btap = 0;
    p.M = 512; p.N = 512; p.K = 256; p.taps = 1;
    p.Cf = WF(ABUF_); p.cz = 262144; p.cld = 512;
    k_gemm<SM_F32, ACT_NONE><<<dim3(8, 8, 32), dim3(256), 0, stream>>>(p);
  }
  k_softmax<<<dim3(16384), dim3(256), 0, stream>>>(WF(ABUF_), WB(ABF_));

  // ---- teacher + prenet + context ----
  k_teacher<<<dim3(3072), dim3(256), 0, stream>>>(mels, ictx, WB(TEA_));
  {
    GP p{}; p.A = WB(TEA_); p.az = 0; p.rshift = 8; p.rpitch = 256;
    p.B = WB(W1P_); p.bz = 0; p.btap = 0;
    p.M = 8192; p.N = 128; p.K = 96; p.taps = 1;
    p.Cb = WB(P1_); p.cz = 0; p.cld = 128; p.bias = pb1; p.s1 = ps1;
    k_gemm<SM_BF16, ACT_PSINE><<<dim3(128, 2, 1), dim3(256), 0, stream>>>(p);
  }
  {
    GP p{}; p.A = WB(P1_); p.az = 0; p.rshift = 8; p.rpitch = 256;
    p.B = pW2; p.bz = 0; p.btap = 0;
    p.M = 8192; p.N = 128; p.K = 128; p.taps = 1;
    p.Cb = WB(P2_); p.cz = 0; p.cld = 128; p.bias = pb2; p.s1 = ps2;
    k_gemm<SM_BF16, ACT_PSINE><<<dim3(128, 2, 1), dim3(256), 0, stream>>>(p);
  }
  {
    GP p{}; p.A = WB(P2_); p.az = 0; p.rshift = 8; p.rpitch = 256;
    p.B = pW3; p.bz = 0; p.btap = 0;
    p.M = 8192; p.N = 64; p.K = 128; p.taps = 1;
    p.Cb = WB(CTXP_); p.cz = 0; p.cld = 64; p.p2 = 268; p.pad2 = 12; p.bias = pb3; p.biasz = 0;
    k_gemm<SM_PADROW, ACT_BIAS><<<dim3(128, 1, 1), dim3(256), 0, stream>>>(p);
  }
  k_ctxcopy<<<dim3(2048), dim3(256), 0, stream>>>(WB(CTXP_), WB(CTXL_));

  // ---- causal Q conv ----
  {
    GP p{}; p.A = WB(CTXP_); p.az = 0; p.rshift = 8; p.rpitch = 268;
    p.B = WB(WQT_); p.bz = 0; p.btap = 512L * 64;
    p.M = 8192; p.N = 512; p.K = 64; p.taps = 13;
    p.Cb = WB(QB_); p.cz = 0; p.cld = 512; p.bias = bq; p.biasz = 0;
    k_gemm<SM_BF16, ACT_BIAS><<<dim3(128, 8, 1), dim3(256), 0, stream>>>(p);
  }
  // ---- o = a @ q ----
  {
    GP p{}; p.A = WB(QB_); p.az = 256L * 512; p.rshift = 8; p.rpitch = 256;
    p.B = WB(ABF_); p.bz = 512L * 512; p.btap = 0;
    p.M = 256; p.N = 512; p.K = 512; p.taps = 1;
    p.Cb = WB(OB_); p.cz = 256L * 512; p.cld = 512;
    k_gemm<SM_BF16, ACT_NONE><<<dim3(4, 8, 32), dim3(256), 0, stream>>>(p);
  }
  // ---- dec_in ----
  {
    GP p{}; p.A = WB(OB_); p.az = 0; p.rshift = 8; p.rpitch = 256;
    p.B = prW; p.bz = 0; p.btap = 0;
    p.M = 8192; p.N = 64; p.K = 512; p.taps = 1;
    p.Cb = WB(DIN_); p.cz = 0; p.cld = 64;
    p.bias = prb; p.aux = WB(CTXL_); p.auxld = 64; p.gamma = gam;
    k_gemm<SM_BF16, ACT_DECIN><<<dim3(128, 1, 1), dim3(256), 0, stream>>>(p);
  }
  // ---- decoder layer0 pregates + flag-dataflow scan ----
  {
    GP p{}; p.A = WB(DIN_); p.az = 0; p.rshift = 8; p.rpitch = 256;
    p.B = dWih0; p.bz = 0; p.btap = 0;
    p.M = 8192; p.N = 1024; p.K = 64; p.taps = 1;
    p.Cf = WF(DPG0_); p.cz = 0; p.cld = 1024; p.bias = db; p.biasz = 0;
    k_gemm<SM_F32, ACT_BIAS><<<dim3(128, 16, 1), dim3(256), 0, stream>>>(p);
  }
  // decoder flags live in the (now free) ABUF region; zero per launch
  hipMemsetAsync(WF(ABUF_), 0, 256 * 16 * 4, stream);
  k_hdec_init<<<dim3(128), dim3(256), 0, stream>>>(WF(HFIN_), WF(HDEC_));
  k_dec_scan<<<dim3(256), dim3(256), 0, stream>>>(
      WF(DPG0_), dWihr, dWhh, db, WF(HDEC_), WF(CFIN_), WB(TOP_), (unsigned*)WF(ABUF_));

  // ---- fc + outputs + stop ----
  {
    GP p{}; p.A = WB(TOP_); p.az = 0; p.rshift = 8; p.rpitch = 256;
    p.B = fcW; p.bz = 0; p.btap = 0;
    p.M = 8192; p.N = 80; p.K = 256; p.taps = 1;
    p.Cf = WF(OUTF_); p.p2 = 80; p.tp = 256; p.bias = fcb; p.biasz = 0;
    k_gemm<SM_TNF32, ACT_BIAS><<<dim3(128, 2, 1), dim3(256), 0, stream>>>(p);
  }
  k_outcopy1<<<dim3(2560), dim3(256), 0, stream>>>(WF(OUTF_), out0);
  k_outcopy2<<<dim3(2560), dim3(256), 0, stream>>>(WF(OUTF_), WB(OUTT_));
  k_stop<<<dim3(32), dim3(256), 0, stream>>>(WB(TOP_), WF(HFIN_), sW, sb, out2);

  // ---- postnet ----
  {
    GP p{}; p.A = WB(OUTT_); p.az = 0; p.rshift = 8; p.rpitch = 260;
    p.B = WB(PN0T_); p.bz = 0; p.btap = 512L * 96;
    p.M = 8192; p.N = 512; p.K = 96; p.taps = 5;
    p.Cb = WB(PN1_); p.cz = 0; p.cld = 512; p.p2 = 260; p.pad2 = 2;
    p.bias = pnb0; p.s1 = bns; p.s2 = bnb; p.s3 = cv[44];
    k_gemm<SM_PADROW, ACT_POSTNET><<<dim3(128, 8, 1), dim3(256), 0, stream>>>(p);
  }
  for (int s3 = 0; s3 < 3; ++s3) {
    GP p{}; p.A = (s3 & 1) ? WB(PN2_) : WB(PN1_); p.az = 0; p.rshift = 8; p.rpitch = 260;
    p.B = WB(PNMT_) + (long)s3 * 512 * 512; p.bz = 0; p.btap = 1536L * 512;
    p.M = 8192; p.N = 512; p.K = 512; p.taps = 5;
    p.Cb = (s3 & 1) ? WB(PN1_) : WB(PN2_); p.cz = 0; p.cld = 512; p.p2 = 260; p.pad2 = 2;
    p.bias = pnbm + s3 * 512; p.s1 = bns + (s3 + 1) * 512; p.s2 = bnb + (s3 + 1) * 512; p.s3 = cv[44] + (s3 + 1) * 512;
    k_gemm<SM_PADROW, ACT_POSTNET><<<dim3(128, 8, 1), dim3(256), 0, stream>>>(p);
  }
  {
    GP p{}; p.A = WB(PN2_); p.az = 0; p.rshift = 8; p.rpitch = 260;
    p.B = WB(PN4T_); p.bz = 0; p.btap = 80L * 512;
    p.M = 8192; p.N = 80; p.K = 512; p.taps = 5;
    p.Cf = out1; p.p2 = 80; p.tp = 256;
    p.bias = pnb4; p.s1 = bnso; p.s2 = bnbo; p.res = WF(OUTF_);
    k_gemm<SM_RESOUT, ACT_RESADD><<<dim3(128, 2, 1), dim3(256), 0, stream>>>(p);
  }
}

// Round 7
// 7685.741 us; speedup vs baseline: 3.6157x; 3.0566x over previous
//
#include <hip/hip_runtime.h>
#include <hip/hip_bf16.h>

typedef __hip_bfloat16 bf16;
#define DEV __device__ __forceinline__

typedef __attribute__((ext_vector_type(8))) short bfrag;
typedef __attribute__((ext_vector_type(4))) float facc;

// ---------------- ws layout (units of f32) ----------------
#define PG_    0L
#define ABUF_  0L          // also decoder flag region (16KB)
#define DPG0_  8388608L
#define Y0_    16777216L
#define ENCT_  18874368L
#define KB_    20975872L
#define VB_    23073024L
#define ABF_   25170176L
#define TEA_   29364480L
#define P1_    29757696L
#define P2_    30281984L
#define CTXP_  30806272L
#define CTXL_  31080704L
#define QB_    31342848L
#define OB_    33440000L
#define DIN_   35537152L
#define TOP_   35799296L
#define OUTF_  36847872L
#define OUTT_  37503232L
#define PN1_   37902592L   // also enc WT0 scratch before postnet
#define PN2_   40032512L   // also enc WT1 scratch before postnet
#define WKT_   42162432L
#define WVT_   43342080L
#define WQT_   44521728L
#define W1P_   44734720L
#define PN0T_  44740864L
#define PNMT_  44863744L
#define PN4T_  46829824L
#define HDEC_  46964992L   // u32 packed bf16 pairs [4][2][32][128]
#define HFIN_  47030528L
#define CFIN_  47063296L
#define FLAG_  47096320L   // 1 uint
#define CVT_   47096336L
#define WS_NEED_BYTES (52092992L * 4L)

// ---------------- helpers ----------------
DEV float b2f(bf16 x) { return __bfloat162float(x); }
DEV bf16  f2b(float x) { return __float2bfloat16(x); }
DEV float flo(unsigned v) { union { unsigned u; float f; } c; c.u = v << 16; return c.f; }
DEV float fhi(unsigned v) { union { unsigned u; float f; } c; c.u = v & 0xffff0000u; return c.f; }
DEV unsigned bu(bf16 x) { union { bf16 b; unsigned short u; } c; c.b = x; return (unsigned)c.u; }
DEV unsigned pk2(float a, float b) { return bu(f2b(a)) | (bu(f2b(b)) << 16); }
DEV float sigm(float x) { return 1.0f / (1.0f + __expf(-x)); }

// relaxed single-flag spin (no cache invalidate storms)
DEV void spin_ge(unsigned* f, unsigned tgt) {
  while (__hip_atomic_load(f, __ATOMIC_RELAXED, __HIP_MEMORY_SCOPE_AGENT) < tgt)
    __builtin_amdgcn_s_sleep(2);
}

DEV void acc8(float& a, uint4 w, const float* x) {
  a += flo(w.x) * x[0] + fhi(w.x) * x[1] + flo(w.y) * x[2] + fhi(w.y) * x[3]
     + flo(w.z) * x[4] + fhi(w.z) * x[5] + flo(w.w) * x[6] + fhi(w.w) * x[7];
}

// ---------------- dtype detect + convert ----------------
__global__ void k_flag(const unsigned short* psw, unsigned* flag) {
  if (threadIdx.x == 0 && blockIdx.x == 0) *flag = (psw[0] != 0) ? 1u : 0u;
}

__global__ void k_cvt(const void* src, bf16* dst, long n, const unsigned* flag) {
  long i = (long)blockIdx.x * 256 + threadIdx.x;
  const long stride = (long)gridDim.x * 256;
  if (*flag) {
    const bf16* s = (const bf16*)src;
    for (; i < n; i += stride) dst[i] = s[i];
  } else {
    const float* s = (const float*)src;
    for (; i < n; i += stride) dst[i] = f2b(s[i]);
  }
}

// ---------------- generic GEMM (MFMA bf16, fused epilogues) ----------------
enum { ACT_NONE = 0, ACT_BIAS = 1, ACT_PSINE = 2, ACT_POSTNET = 3, ACT_DECIN = 4, ACT_RESADD = 5 };
enum { SM_F32 = 0, SM_BF16 = 1, SM_PADROW = 2, SM_NCT = 3, SM_TNF32 = 4, SM_RESOUT = 5 };

struct GP {
  const bf16* A; const bf16* B;
  long az, bz, btap;
  int M, N, K, taps;
  int rshift, rpitch;
  float* Cf; bf16* Cb;
  long cz; int cld;
  int p2, pad2, tmax, tp;
  const bf16* bias; long biasz;
  const bf16* s1; const bf16* s2; const bf16* s3;
  const bf16* aux; int auxld;
  const bf16* gamma; const float* res;
};

template<int SM, int ACTM>
__global__ __launch_bounds__(256) void k_gemm(GP p) {
  __shared__ bf16 As[64][40];
  __shared__ bf16 Bs[64][40];
  const int tid = threadIdx.x;
  const int z = blockIdx.z;
  const bf16* Ab = p.A + (long)z * p.az;
  const bf16* Bb = p.B + (long)z * p.bz;
  const int m0 = blockIdx.x * 64, c0 = blockIdx.y * 64;
  const int w = tid >> 6, l = tid & 63;
  const int lrow = tid & 63, lk = (tid >> 6) * 8;
  facc acc[4];
  #pragma unroll
  for (int s = 0; s < 4; ++s) acc[s] = facc{0.f, 0.f, 0.f, 0.f};
  const int am = m0 + lrow;
  const int grp = am >> p.rshift;
  const long arowbase = (long)grp * p.rpitch + (am - (grp << p.rshift));
  const int brow = c0 + lrow;
  const bool bok = brow < p.N;
  const int arow_f = w * 16 + (l & 15);       // fragment A row within tile
  const int kf = (l >> 4) * 8;                // fragment k offset
  for (int j = 0; j < p.taps; ++j) {
    const bf16* Aj = Ab + (arowbase + j) * (long)p.K + lk;
    const bf16* Bj = Bb + (long)j * p.btap + (long)brow * p.K + lk;
    for (int k0 = 0; k0 < p.K; k0 += 32) {
      __syncthreads();
      {
        uint4 av = *(const uint4*)(Aj + k0);
        *(uint4*)&As[lrow][lk] = av;
        uint4 bvv; bvv.x = bvv.y = bvv.z = bvv.w = 0u;
        if (bok) bvv = *(const uint4*)(Bj + k0);
        *(uint4*)&Bs[lrow][lk] = bvv;
      }
      __syncthreads();
      bfrag af = *(const bfrag*)&As[arow_f][kf];
      #pragma unroll
      for (int s = 0; s < 4; ++s) {
        bfrag bf = *(const bfrag*)&Bs[s * 16 + (l & 15)][kf];
        acc[s] = __builtin_amdgcn_mfma_f32_16x16x32_bf16(af, bf, acc[s], 0, 0, 0);
      }
    }
  }
  float gf = 0.f;
  if constexpr (ACTM == ACT_DECIN) gf = b2f(p.gamma[0]);
  #pragma unroll
  for (int s = 0; s < 4; ++s) {
    const int c = c0 + s * 16 + (l & 15);
    if (c >= p.N) continue;
    #pragma unroll
    for (int i = 0; i < 4; ++i) {
      const int m = m0 + w * 16 + ((l >> 4) << 2) + i;
      const int n_ = m >> 8, t_ = m & 255;
      float x = acc[s][i];
      if constexpr (ACTM == ACT_BIAS) x += b2f(p.bias[(long)z * p.biasz + c]);
      else if constexpr (ACTM == ACT_PSINE) x = sinf(x + b2f(p.bias[c])) * b2f(p.s1[c]);
      else if constexpr (ACTM == ACT_POSTNET) x = sinf((x + b2f(p.bias[c])) * b2f(p.s1[c]) + b2f(p.s2[c])) * b2f(p.s3[c]);
      else if constexpr (ACTM == ACT_DECIN) x = b2f(p.aux[(long)m * p.auxld + c]) + gf * (x + b2f(p.bias[c]));
      else if constexpr (ACTM == ACT_RESADD) x = (x + b2f(p.bias[c])) * b2f(p.s1[c]) + b2f(p.s2[c]);
      if constexpr (SM == SM_F32) p.Cf[(long)z * p.cz + (long)m * p.cld + c] = x;
      else if constexpr (SM == SM_BF16) p.Cb[(long)z * p.cz + (long)m * p.cld + c] = f2b(x);
      else if constexpr (SM == SM_PADROW) p.Cb[((long)n_ * p.p2 + p.pad2 + t_) * (long)p.cld + c] = f2b(x);
      else if constexpr (SM == SM_NCT) { if (t_ < p.tmax) p.Cb[((long)n_ * p.p2 + c) * (long)p.tp + t_] = f2b(x); }
      else if constexpr (SM == SM_TNF32) { const int nn = m & 31, tt = m >> 5; p.Cf[((long)nn * p.p2 + c) * (long)p.tp + tt] = x; }
      else if constexpr (SM == SM_RESOUT) { const long off = ((long)n_ * p.p2 + c) * (long)p.tp + t_; p.Cf[off] = x + p.res[off]; }
    }
  }
}

// ---------------- weight transpose for enc scan: [2][1024][256] -> [2][32][1024][8] ----------------
__global__ void k_wtr2(const bf16* __restrict__ in, bf16* __restrict__ out) {
  long i = (long)blockIdx.x * 256 + threadIdx.x;
  if (i >= 524288L) return;
  int jj = (int)(i & 7);
  int r = (int)((i >> 3) & 1023);
  int k8 = (int)((i >> 13) & 31);
  int d = (int)(i >> 18);
  out[i] = in[((long)d * 1024 + r) * 256 + k8 * 8 + jj];
}

// ---------------- encoder LSTM scan: one block per (dir,batch), coalesced k-major weights ----
__global__ __launch_bounds__(256) void k_enc_scan(
    const float* __restrict__ pg,      // [2][32][256][1024]
    const bf16* __restrict__ WT,       // [2][32 k8][1024 r][8]
    bf16* __restrict__ ycat,           // [32][256][512]
    float* __restrict__ hfin, float* __restrict__ cfin,
    int layer)
{
  __shared__ float Hs[2][256];
  const int u = threadIdx.x;
  const int d = (int)(blockIdx.x >> 5);
  const int n = (int)(blockIdx.x & 31);
  const bf16* Wd = WT + (long)d * 32 * 1024 * 8;
  const float* pgn = pg + (long)(d * 32 + n) * 256 * 1024;
  float cst = 0.f;
  Hs[0][u] = 0.f;
  __syncthreads();
  for (int it = 0; it < 256; ++it) {
    const int s = d ? (255 - it) : it;
    const int par = it & 1;
    const float* pgs = pgn + (long)s * 1024;
    float a0 = pgs[u], a1 = pgs[256 + u], a2 = pgs[512 + u], a3 = pgs[768 + u];
    #pragma unroll 2
    for (int k8 = 0; k8 < 32; ++k8) {
      float x[8];
      *(float4*)&x[0] = *(const float4*)&Hs[par][k8 * 8];
      *(float4*)&x[4] = *(const float4*)&Hs[par][k8 * 8 + 4];
      const bf16* wb = Wd + ((long)k8 * 1024 + u) * 8;
      acc8(a0, *(const uint4*)(wb), x);
      acc8(a1, *(const uint4*)(wb + 2048), x);
      acc8(a2, *(const uint4*)(wb + 4096), x);
      acc8(a3, *(const uint4*)(wb + 6144), x);
    }
    cst = sigm(a1) * cst + sigm(a0) * tanhf(a2);
    float h = sigm(a3) * tanhf(cst);
    Hs[par ^ 1][u] = h;
    ycat[((long)n * 256 + s) * 512 + d * 256 + u] = f2b(h);
    if (it == 255) {
      hfin[((long)(layer * 2 + d) * 32 + n) * 256 + u] = h;
      cfin[((long)(layer * 2 + d) * 32 + n) * 256 + u] = cst;
    }
    __syncthreads();
  }
}

// ---------------- decoder 4-layer LSTM: coherence-point atomics, packed-bf16 h ----------------
__global__ __launch_bounds__(256) void k_dec_scan(
    const float* __restrict__ dpg0,     // [32][256][1024]
    const bf16* __restrict__ Wih_rest,  // [3][1024][256]
    const bf16* __restrict__ Whh,       // [4][1024][256]
    const bf16* __restrict__ dec_b,     // [4][1024]
    unsigned* __restrict__ hdec,        // [4][2][32][128] u32 (bf16 pairs)
    const float* __restrict__ cfin,     // [4][32][256]
    bf16* __restrict__ top,             // [256][32][256]
    unsigned* __restrict__ flags)       // [256] x stride 16 u32
{
  __shared__ bf16 Wl[16][520];
  __shared__ bf16 XH[32][536];
  __shared__ float Gs[16 * 33];
  __shared__ float Hst[128];
  const int tid = threadIdx.x;
  const int layer = (int)(blockIdx.x >> 6);
  const int g = (int)(blockIdx.x & 63);
  const int u0 = g * 4;
  const int kstart = (layer == 0) ? 256 : 0;
  {
    const int r = tid >> 4, seg = tid & 15;
    const int grow = (r >> 2) * 256 + u0 + (r & 3);
    const int kk = seg * 32;
    const bool part0 = kk < 256;
    if (!(part0 && layer == 0)) {
      const bf16* wp = part0
          ? (Wih_rest + ((long)(layer - 1) * 1024 + grow) * 256 + kk)
          : (Whh + ((long)layer * 1024 + grow) * 256 + (kk - 256));
      for (int q = 0; q < 32; q += 8) {
        uint4 v = *(const uint4*)(wp + q);
        *(uint4*)&Wl[r][kk + q] = v;
      }
    }
  }
  const int pn = tid >> 2, pu = tid & 3;
  float cst = 0.f, bi0 = 0.f, bi1 = 0.f, bi2 = 0.f, bi3 = 0.f;
  if (tid < 128) {
    cst = cfin[((long)layer * 32 + pn) * 256 + u0 + pu];
    if (layer > 0) {
      bi0 = b2f(dec_b[layer * 1024 + u0 + pu]);
      bi1 = b2f(dec_b[layer * 1024 + 256 + u0 + pu]);
      bi2 = b2f(dec_b[layer * 1024 + 512 + u0 + pu]);
      bi3 = b2f(dec_b[layer * 1024 + 768 + u0 + pu]);
    }
  }
  __syncthreads();
  for (int t = 0; t < 256; ++t) {
    if (tid < 64) {
      if (layer > 0) spin_ge(&flags[((layer - 1) * 64 + tid) * 16], (unsigned)(t + 1));
    } else if (tid < 128) {
      if (t >= 1) spin_ge(&flags[(layer * 64 + (tid - 64)) * 16], (unsigned)t);
    } else if (tid < 192) {
      if (layer < 3 && t >= 2) spin_ge(&flags[((layer + 1) * 64 + (tid - 128)) * 16], (unsigned)(t - 1));
    }
    __syncthreads();
    const int rp = (t + layer + 1) & 1, wpar = (t + layer) & 1;
    {
      const int n = tid >> 3, seg = tid & 7;
      if (layer > 0 || seg >= 4) {
        const unsigned* src = (seg < 4)
            ? (hdec + (((long)(layer - 1) * 2 + rp) * 32 + n) * 128 + seg * 32)
            : (hdec + (((long)layer * 2 + rp) * 32 + n) * 128 + (seg - 4) * 32);
        const int base = seg * 64;
        #pragma unroll
        for (int q = 0; q < 32; q += 4) {
          unsigned long long v01 = __hip_atomic_load((const unsigned long long*)(src + q),
                                                     __ATOMIC_RELAXED, __HIP_MEMORY_SCOPE_AGENT);
          unsigned long long v23 = __hip_atomic_load((const unsigned long long*)(src + q + 2),
                                                     __ATOMIC_RELAXED, __HIP_MEMORY_SCOPE_AGENT);
          *(uint4*)&XH[n][base + q * 2] =
              make_uint4((unsigned)v01, (unsigned)(v01 >> 32), (unsigned)v23, (unsigned)(v23 >> 32));
        }
      }
    }
    __syncthreads();
    {
      const int r = tid & 15, n0 = (tid >> 4) * 2;
      float a0 = 0, a1 = 0;
      const bf16* wr = &Wl[r][0];
      const bf16* xa = &XH[n0][0];
      const bf16* xb = &XH[n0 + 1][0];
      #pragma unroll 4
      for (int k = kstart; k < 512; k += 4) {
        uint2 wv = *(const uint2*)(wr + k);
        uint2 va = *(const uint2*)(xa + k);
        uint2 vb = *(const uint2*)(xb + k);
        float w0 = flo(wv.x), w1 = fhi(wv.x), w2 = flo(wv.y), w3 = fhi(wv.y);
        a0 += w0 * flo(va.x) + w1 * fhi(va.x) + w2 * flo(va.y) + w3 * fhi(va.y);
        a1 += w0 * flo(vb.x) + w1 * fhi(vb.x) + w2 * flo(vb.y) + w3 * fhi(vb.y);
      }
      Gs[r * 33 + n0] = a0;
      Gs[r * 33 + n0 + 1] = a1;
    }
    __syncthreads();
    if (tid < 128) {
      float g0 = Gs[(0 * 4 + pu) * 33 + pn] + bi0;
      float g1 = Gs[(1 * 4 + pu) * 33 + pn] + bi1;
      float g2 = Gs[(2 * 4 + pu) * 33 + pn] + bi2;
      float g3 = Gs[(3 * 4 + pu) * 33 + pn] + bi3;
      if (layer == 0) {
        const float* pp = dpg0 + ((long)pn * 256 + t) * 1024;
        g0 += pp[u0 + pu]; g1 += pp[256 + u0 + pu];
        g2 += pp[512 + u0 + pu]; g3 += pp[768 + u0 + pu];
      }
      cst = sigm(g1) * cst + sigm(g0) * tanhf(g2);
      float h = sigm(g3) * tanhf(cst);
      Hst[tid] = h;
      if (layer == 3) top[((long)t * 32 + pn) * 256 + u0 + pu] = f2b(h);
    }
    __syncthreads();
    if (tid < 64) {
      const int hn = tid >> 1, pr = tid & 1;
      unsigned v = pk2(Hst[hn * 4 + pr * 2], Hst[hn * 4 + pr * 2 + 1]);
      __hip_atomic_store(&hdec[(((long)layer * 2 + wpar) * 32 + hn) * 128 + (u0 >> 1) + pr], v,
                         __ATOMIC_RELAXED, __HIP_MEMORY_SCOPE_AGENT);
    }
    asm volatile("s_waitcnt vmcnt(0)" ::: "memory");
    __syncthreads();
    if (tid == 0)
      __hip_atomic_store(&flags[(layer * 64 + g) * 16], (unsigned)(t + 1),
                         __ATOMIC_RELAXED, __HIP_MEMORY_SCOPE_AGENT);
  }
}

// ---------------- small kernels ----------------
__global__ void k_wtr(const void* __restrict__ in, bf16* __restrict__ out,
                      int Cout, int Cin, int Cpad, int taps, int tstride, long total,
                      const unsigned* __restrict__ flag) {
  long i = (long)blockIdx.x * 256 + threadIdx.x;
  if (i >= total) return;
  int ci = (int)(i % Cpad); long r = i / Cpad; int co = (int)(r % Cout); int j = (int)(r / Cout);
  float v = 0.f;
  if (ci < Cin) {
    long idx = ((long)co * Cin + ci) * tstride + j;
    v = (*flag) ? b2f(((const bf16*)in)[idx]) : ((const float*)in)[idx];
  }
  out[i] = f2b(v);
}

__global__ void k_softmax(const float* __restrict__ raw, bf16* __restrict__ out) {
  __shared__ float red[256];
  const long row = blockIdx.x;
  const float* r = raw + row * 512;
  const int tid = threadIdx.x;
  float a = r[tid], b = r[tid + 256];
  red[tid] = fmaxf(a, b);
  __syncthreads();
  for (int s = 128; s > 0; s >>= 1) { if (tid < s) red[tid] = fmaxf(red[tid], red[tid + s]); __syncthreads(); }
  const float m = red[0];
  __syncthreads();
  float e0 = __expf(a - m), e1 = __expf(b - m);
  red[tid] = e0 + e1;
  __syncthreads();
  for (int s = 128; s > 0; s >>= 1) { if (tid < s) red[tid] += red[tid + s]; __syncthreads(); }
  const float inv = 1.f / red[0];
  out[row * 512 + tid] = f2b(e0 * inv);
  out[row * 512 + tid + 256] = f2b(e1 * inv);
}

__global__ void k_teacher(const bf16* __restrict__ mels, const bf16* __restrict__ ictx, bf16* __restrict__ out) {
  long i = (long)blockIdx.x * 256 + threadIdx.x;
  if (i >= 8192L * 96) return;
  int c = (int)(i % 96); long m = i / 96; int n = (int)(m >> 8), t = (int)(m & 255);
  float v = 0.f;
  if (c < 80) v = (t == 0) ? b2f(ictx[c]) : b2f(mels[((long)n * 80 + c) * 256 + (t - 1)]);
  out[i] = f2b(v);
}

__global__ void k_ctxcopy(const bf16* __restrict__ ctxp, bf16* __restrict__ ctxl) {
  long i = (long)blockIdx.x * 256 + threadIdx.x;
  if (i >= 8192L * 64) return;
  int c = (int)(i & 63); long m = i >> 6; int n = (int)(m >> 8), t = (int)(m & 255);
  ctxl[i] = ctxp[((long)n * 268 + 12 + t) * 64 + c];
}

__global__ void k_hdec_init(const float* __restrict__ hfin, unsigned* __restrict__ hdec) {
  int i = blockIdx.x * 256 + threadIdx.x;
  if (i >= 16384) return;
  int l = i >> 12, r = i & 4095;
  unsigned v = pk2(hfin[(long)l * 8192 + r * 2], hfin[(long)l * 8192 + r * 2 + 1]);
  hdec[((long)l * 2 + 0) * 4096 + r] = v;
  hdec[((long)l * 2 + 1) * 4096 + r] = v;
}

__global__ void k_outcopy1(const float* __restrict__ of, float* __restrict__ o) {
  long i = (long)blockIdx.x * 256 + threadIdx.x;
  if (i < 655360L) o[i] = of[i];
}

__global__ void k_outcopy2(const float* __restrict__ of, bf16* __restrict__ ot) {
  long i = (long)blockIdx.x * 256 + threadIdx.x;
  if (i >= 655360L) return;
  int c = (int)(i % 80); long m = i / 80; int n = (int)(m >> 8), t = (int)(m & 255);
  ot[((long)n * 260 + 2 + t) * 96 + c] = f2b(of[((long)n * 80 + c) * 256 + t]);
}

__global__ void k_stop(const bf16* __restrict__ top, const float* __restrict__ hfin,
                       const bf16* __restrict__ sW, const bf16* __restrict__ sb, float* __restrict__ out) {
  int i = blockIdx.x * 256 + threadIdx.x;
  if (i >= 8192) return;
  int n = i >> 8, t = i & 255;
  float acc = b2f(sb[0]);
  const bf16* tr = top + ((long)t * 32 + n) * 256;
  for (int h = 0; h < 256; ++h) acc += b2f(tr[h]) * b2f(sW[h]);
  const float* er = hfin + ((long)2 * 32 + n) * 256;
  for (int h = 0; h < 256; ++h) acc += er[h] * b2f(sW[256 + h]);
  out[(long)n * 256 + t] = acc;
}

// ---------------- host ----------------
extern "C" void kernel_launch(void* const* d_in, const int* in_sizes, int n_in,
                              void* d_out, int out_size, void* d_ws, size_t ws_size,
                              hipStream_t stream) {
  (void)in_sizes; (void)n_in; (void)out_size;
  if (ws_size < (size_t)WS_NEED_BYTES) return;

  float* ws = (float*)d_ws;
  float* out0 = (float*)d_out;
  float* out1 = out0 + 655360L;
  float* out2 = out0 + 1310720L;
  #define WF(off) (ws + (off))
  #define WB(off) ((bf16*)(ws + (off)))
  unsigned* flagp = (unsigned*)WF(FLAG_);

  // zero padded buffers (PN1/PN2 zeroed later: they hold enc WT scratch first)
  hipMemsetAsync(WF(ENCT_), 0, 2101248L * 4, stream);
  hipMemsetAsync(WF(KB_), 0, 2097152L * 4, stream);
  hipMemsetAsync(WF(VB_), 0, 2097152L * 4, stream);
  hipMemsetAsync(WF(CTXP_), 0, 274432L * 4, stream);
  hipMemsetAsync(WF(OUTT_), 0, 399360L * 4, stream);

  // dtype flag + input conversion
  k_flag<<<dim3(1), dim3(64), 0, stream>>>((const unsigned short*)d_in[44], flagp);
  bf16* cv[48] = {};
  {
    struct CvtEnt { int idx; long n; };
    static const CvtEnt cvts[] = {
      {0, 4194304}, {1, 655360}, {5, 2097152}, {6, 1048576}, {7, 4096},
      {9, 512}, {11, 512}, {13, 512}, {14, 80},
      {16, 128}, {17, 128}, {18, 16384}, {19, 128}, {20, 128}, {21, 8192}, {22, 64},
      {23, 32768}, {24, 64}, {25, 1},
      {26, 65536}, {27, 786432}, {28, 1048576}, {29, 4096},
      {30, 20480}, {31, 80}, {32, 512}, {33, 1},
      {35, 512}, {37, 1536}, {39, 80},
      {40, 2048}, {41, 2048}, {42, 80}, {43, 80}, {44, 2048},
    };
    bf16* arena = WB(CVT_);
    long pos = 0;
    for (const auto& c : cvts) {
      bf16* dst = arena + pos;
      long g = (c.n + 255) / 256; if (g > 2048) g = 2048;
      k_cvt<<<dim3((unsigned)g), dim3(256), 0, stream>>>(d_in[c.idx], dst, c.n, flagp);
      cv[c.idx] = dst;
      pos += (c.n + 15) & ~15L;
    }
  }

  const bf16* enc_out = cv[0];
  const bf16* mels    = cv[1];
  const bf16* eWih    = cv[5];
  const bf16* eWhh    = cv[6];
  const bf16* eb      = cv[7];
  const bf16* bk      = cv[9];
  const bf16* bv      = cv[11];
  const bf16* bq      = cv[13];
  const bf16* ictx    = cv[14];
  const bf16* pb1     = cv[16];
  const bf16* ps1     = cv[17];
  const bf16* pW2     = cv[18];
  const bf16* pb2     = cv[19];
  const bf16* ps2     = cv[20];
  const bf16* pW3     = cv[21];
  const bf16* pb3     = cv[22];
  const bf16* prW     = cv[23];
  const bf16* prb     = cv[24];
  const bf16* gam     = cv[25];
  const bf16* dWih0   = cv[26];
  const bf16* dWihr   = cv[27];
  const bf16* dWhh    = cv[28];
  const bf16* db      = cv[29];
  const bf16* fcW     = cv[30];
  const bf16* fcb     = cv[31];
  const bf16* sW      = cv[32];
  const bf16* sb      = cv[33];
  const bf16* pnb0    = cv[35];
  const bf16* pnbm    = cv[37];
  const bf16* pnb4    = cv[39];
  const bf16* bns     = cv[40];
  const bf16* bnb     = cv[41];
  const bf16* bnso    = cv[42];
  const bf16* bnbo    = cv[43];

  auto tr = [&](const void* in, bf16* o, int Cout, int Cin, int Cpad, int to, int ts) {
    long tot = (long)to * Cout * Cpad;
    k_wtr<<<dim3((unsigned)((tot + 255) / 256)), dim3(256), 0, stream>>>(in, o, Cout, Cin, Cpad, to, ts, tot, flagp);
  };
  tr(d_in[8],  WB(WKT_), 512, 512, 512, 9, 9);
  tr(d_in[10], WB(WVT_), 512, 512, 512, 9, 9);
  tr(d_in[12], WB(WQT_), 512, 64, 64, 13, 24);
  tr(d_in[15], WB(W1P_), 128, 80, 96, 1, 1);
  tr(d_in[34], WB(PN0T_), 512, 80, 96, 5, 5);
  tr(d_in[36], WB(PNMT_), 1536, 512, 512, 5, 5);
  tr(d_in[38], WB(PN4T_), 80, 512, 512, 5, 5);

  // ---- encoder layer 0 ----
  {
    GP p{}; p.A = enc_out; p.az = 0; p.rshift = 8; p.rpitch = 256;
    p.B = eWih; p.bz = 1024L * 512; p.btap = 0;
    p.M = 8192; p.N = 1024; p.K = 512; p.taps = 1;
    p.Cf = WF(PG_); p.cz = 8388608; p.cld = 1024; p.bias = eb; p.biasz = 1024;
    k_gemm<SM_F32, ACT_BIAS><<<dim3(128, 16, 2), dim3(256), 0, stream>>>(p);
  }
  k_wtr2<<<dim3(2048), dim3(256), 0, stream>>>(eWhh, WB(PN1_));
  k_enc_scan<<<dim3(64), dim3(256), 0, stream>>>(
      WF(PG_), WB(PN1_), WB(Y0_), WF(HFIN_), WF(CFIN_), 0);
  // ---- encoder layer 1 ----
  {
    GP p{}; p.A = WB(Y0_); p.az = 0; p.rshift = 8; p.rpitch = 256;
    p.B = eWih + 2L * 1024 * 512; p.bz = 1024L * 512; p.btap = 0;
    p.M = 8192; p.N = 1024; p.K = 512; p.taps = 1;
    p.Cf = WF(PG_); p.cz = 8388608; p.cld = 1024; p.bias = eb + 2048; p.biasz = 1024;
    k_gemm<SM_F32, ACT_BIAS><<<dim3(128, 16, 2), dim3(256), 0, stream>>>(p);
  }
  k_wtr2<<<dim3(2048), dim3(256), 0, stream>>>(eWhh + 2L * 1024 * 256, WB(PN2_));
  k_enc_scan<<<dim3(64), dim3(256), 0, stream>>>(
      WF(PG_), WB(PN2_), WB(ENCT_), WF(HFIN_), WF(CFIN_), 1);
  // reclaim PN1/PN2 for postnet (pad rows must be zero)
  hipMemsetAsync(WF(PN1_), 0, 2129920L * 4, stream);
  hipMemsetAsync(WF(PN2_), 0, 2129920L * 4, stream);

  // ---- K/V convs ----
  for (int kv = 0; kv < 2; ++kv) {
    GP p{}; p.A = WB(ENCT_); p.az = 0; p.rshift = 8; p.rpitch = 256;
    p.B = kv ? WB(WVT_) : WB(WKT_); p.bz = 0; p.btap = 512L * 512;
    p.M = 8192; p.N = 512; p.K = 512; p.taps = 9;
    p.Cb = kv ? WB(VB_) : WB(KB_); p.cz = 0; p.cld = 512;
    p.p2 = 512; p.tp = 256; p.tmax = 248; p.bias = kv ? bv : bk; p.biasz = 0;
    k_gemm<SM_NCT, ACT_BIAS><<<dim3(128, 8, 1), dim3(256), 0, stream>>>(p);
  }
  // ---- scores + softmax ----
  {
    GP p{}; p.A = WB(KB_); p.az = 512L * 256; p.rshift = 9; p.rpitch = 512;
    p.B = WB(VB_); p.bz = 512L * 256; p.btap = 0;
    p.M = 512; p.N = 512; p.K = 256; p.taps = 1;
    p.Cf = WF(ABUF_); p.cz = 262144; p.cld = 512;
    k_gemm<SM_F32, ACT_NONE><<<dim3(8, 8, 32), dim3(256), 0, stream>>>(p);
  }
  k_softmax<<<dim3(16384), dim3(256), 0, stream>>>(WF(ABUF_), WB(ABF_));

  // ---- teacher + prenet + context ----
  k_teacher<<<dim3(3072), dim3(256), 0, stream>>>(mels, ictx, WB(TEA_));
  {
    GP p{}; p.A = WB(TEA_); p.az = 0; p.rshift = 8; p.rpitch = 256;
    p.B = WB(W1P_); p.bz = 0; p.btap = 0;
    p.M = 8192; p.N = 128; p.K = 96; p.taps = 1;
    p.Cb = WB(P1_); p.cz = 0; p.cld = 128; p.bias = pb1; p.s1 = ps1;
    k_gemm<SM_BF16, ACT_PSINE><<<dim3(128, 2, 1), dim3(256), 0, stream>>>(p);
  }
  {
    GP p{}; p.A = WB(P1_); p.az = 0; p.rshift = 8; p.rpitch = 256;
    p.B = pW2; p.bz = 0; p.btap = 0;
    p.M = 8192; p.N = 128; p.K = 128; p.taps = 1;
    p.Cb = WB(P2_); p.cz = 0; p.cld = 128; p.bias = pb2; p.s1 = ps2;
    k_gemm<SM_BF16, ACT_PSINE><<<dim3(128, 2, 1), dim3(256), 0, stream>>>(p);
  }
  {
    GP p{}; p.A = WB(P2_); p.az = 0; p.rshift = 8; p.rpitch = 256;
    p.B = pW3; p.bz = 0; p.btap = 0;
    p.M = 8192; p.N = 64; p.K = 128; p.taps = 1;
    p.Cb = WB(CTXP_); p.cz = 0; p.cld = 64; p.p2 = 268; p.pad2 = 12; p.bias = pb3; p.biasz = 0;
    k_gemm<SM_PADROW, ACT_BIAS><<<dim3(128, 1, 1), dim3(256), 0, stream>>>(p);
  }
  k_ctxcopy<<<dim3(2048), dim3(256), 0, stream>>>(WB(CTXP_), WB(CTXL_));

  // ---- causal Q conv ----
  {
    GP p{}; p.A = WB(CTXP_); p.az = 0; p.rshift = 8; p.rpitch = 268;
    p.B = WB(WQT_); p.bz = 0; p.btap = 512L * 64;
    p.M = 8192; p.N = 512; p.K = 64; p.taps = 13;
    p.Cb = WB(QB_); p.cz = 0; p.cld = 512; p.bias = bq; p.biasz = 0;
    k_gemm<SM_BF16, ACT_BIAS><<<dim3(128, 8, 1), dim3(256), 0, stream>>>(p);
  }
  // ---- o = a @ q ----
  {
    GP p{}; p.A = WB(QB_); p.az = 256L * 512; p.rshift = 8; p.rpitch = 256;
    p.B = WB(ABF_); p.bz = 512L * 512; p.btap = 0;
    p.M = 256; p.N = 512; p.K = 512; p.taps = 1;
    p.Cb = WB(OB_); p.cz = 256L * 512; p.cld = 512;
    k_gemm<SM_BF16, ACT_NONE><<<dim3(4, 8, 32), dim3(256), 0, stream>>>(p);
  }
  // ---- dec_in ----
  {
    GP p{}; p.A = WB(OB_); p.az = 0; p.rshift = 8; p.rpitch = 256;
    p.B = prW; p.bz = 0; p.btap = 0;
    p.M = 8192; p.N = 64; p.K = 512; p.taps = 1;
    p.Cb = WB(DIN_); p.cz = 0; p.cld = 64;
    p.bias = prb; p.aux = WB(CTXL_); p.auxld = 64; p.gamma = gam;
    k_gemm<SM_BF16, ACT_DECIN><<<dim3(128, 1, 1), dim3(256), 0, stream>>>(p);
  }
  // ---- decoder layer0 pregates + dataflow scan ----
  {
    GP p{}; p.A = WB(DIN_); p.az = 0; p.rshift = 8; p.rpitch = 256;
    p.B = dWih0; p.bz = 0; p.btap = 0;
    p.M = 8192; p.N = 1024; p.K = 64; p.taps = 1;
    p.Cf = WF(DPG0_); p.cz = 0; p.cld = 1024; p.bias = db; p.biasz = 0;
    k_gemm<SM_F32, ACT_BIAS><<<dim3(128, 16, 1), dim3(256), 0, stream>>>(p);
  }
  hipMemsetAsync(WF(ABUF_), 0, 256 * 16 * 4, stream);
  k_hdec_init<<<dim3(64), dim3(256), 0, stream>>>(WF(HFIN_), (unsigned*)WF(HDEC_));
  k_dec_scan<<<dim3(256), dim3(256), 0, stream>>>(
      WF(DPG0_), dWihr, dWhh, db, (unsigned*)WF(HDEC_), WF(CFIN_), WB(TOP_), (unsigned*)WF(ABUF_));

  // ---- fc + outputs + stop ----
  {
    GP p{}; p.A = WB(TOP_); p.az = 0; p.rshift = 8; p.rpitch = 256;
    p.B = fcW; p.bz = 0; p.btap = 0;
    p.M = 8192; p.N = 80; p.K = 256; p.taps = 1;
    p.Cf = WF(OUTF_); p.p2 = 80; p.tp = 256; p.bias = fcb; p.biasz = 0;
    k_gemm<SM_TNF32, ACT_BIAS><<<dim3(128, 2, 1), dim3(256), 0, stream>>>(p);
  }
  k_outcopy1<<<dim3(2560), dim3(256), 0, stream>>>(WF(OUTF_), out0);
  k_outcopy2<<<dim3(2560), dim3(256), 0, stream>>>(WF(OUTF_), WB(OUTT_));
  k_stop<<<dim3(32), dim3(256), 0, stream>>>(WB(TOP_), WF(HFIN_), sW, sb, out2);

  // ---- postnet ----
  {
    GP p{}; p.A = WB(OUTT_); p.az = 0; p.rshift = 8; p.rpitch = 260;
    p.B = WB(PN0T_); p.bz = 0; p.btap = 512L * 96;
    p.M = 8192; p.N = 512; p.K = 96; p.taps = 5;
    p.Cb = WB(PN1_); p.cz = 0; p.cld = 512; p.p2 = 260; p.pad2 = 2;
    p.bias = pnb0; p.s1 = bns; p.s2 = bnb; p.s3 = cv[44];
    k_gemm<SM_PADROW, ACT_POSTNET><<<dim3(128, 8, 1), dim3(256), 0, stream>>>(p);
  }
  for (int s3 = 0; s3 < 3; ++s3) {
    GP p{}; p.A = (s3 & 1) ? WB(PN2_) : WB(PN1_); p.az = 0; p.rshift = 8; p.rpitch = 260;
    p.B = WB(PNMT_) + (long)s3 * 512 * 512; p.bz = 0; p.btap = 1536L * 512;
    p.M = 8192; p.N = 512; p.K = 512; p.taps = 5;
    p.Cb = (s3 & 1) ? WB(PN1_) : WB(PN2_); p.cz = 0; p.cld = 512; p.p2 = 260; p.pad2 = 2;
    p.bias = pnbm + s3 * 512; p.s1 = bns + (s3 + 1) * 512; p.s2 = bnb + (s3 + 1) * 512; p.s3 = cv[44] + (s3 + 1) * 512;
    k_gemm<SM_PADROW, ACT_POSTNET><<<dim3(128, 8, 1), dim3(256), 0, stream>>>(p);
  }
  {
    GP p{}; p.A = WB(PN2_); p.az = 0; p.rshift = 8; p.rpitch = 260;
    p.B = WB(PN4T_); p.bz = 0; p.btap = 80L * 512;
    p.M = 8192; p.N = 80; p.K = 512; p.taps = 5;
    p.Cf = out1; p.p2 = 80; p.tp = 256;
    p.bias = pnb4; p.s1 = bnso; p.s2 = bnbo; p.res = WF(OUTF_);
    k_gemm<SM_RESOUT, ACT_RESADD><<<dim3(128, 2, 1), dim3(256), 0, stream>>>(p);
  }
}